// Round 7
// baseline (655.794 us; speedup 1.0000x reference)
//
#include <hip/hip_runtime.h>
#include <hip/hip_bf16.h>
#include <math.h>

typedef __attribute__((ext_vector_type(8))) short s16x8;
typedef __attribute__((ext_vector_type(4))) short s16x4;
typedef __attribute__((ext_vector_type(4))) float f32x4;

#define MPAD 4352  // = 34*128; local rows exactly 4352, global 4128 (pads read same-call data)
#define LG 2064    // global seq length
#define CT 8       // k-tiles (of 64 keys) per split chunk

__device__ __forceinline__ short f2b(float f) {
  unsigned u = __float_as_uint(f);
  unsigned r = (u + 0x7fffu + ((u >> 16) & 1u)) >> 16;
  return (short)(unsigned short)r;
}
__device__ __forceinline__ float b2f(short s) {
  return __uint_as_float(((unsigned)(unsigned short)s) << 16);
}

// global->LDS direct async copy, 16B per lane. LDS dest must be uniform-base + lane*16.
__device__ __forceinline__ void gl_lds16(const short* g, short* l) {
  __builtin_amdgcn_global_load_lds((const __attribute__((address_space(1))) short*)g,
                                   (__attribute__((address_space(3))) short*)l, 16, 0, 0);
}

// ---------------- transpose + cast: in f32 (K x N) -> out bf16 (N x K) ----------------
__global__ __launch_bounds__(256) void transpose_cast(const float* __restrict__ in,
                                                      short* __restrict__ out,
                                                      int K, int N) {
  __shared__ float tile[32][33];
  int bn = blockIdx.x * 32;
  int bk = blockIdx.y * 32;
  for (int i = threadIdx.y; i < 32; i += 8)
    tile[i][threadIdx.x] = in[(size_t)(bk + i) * N + bn + threadIdx.x];
  __syncthreads();
  for (int i = threadIdx.y; i < 32; i += 8)
    out[(size_t)(bn + i) * K + bk + threadIdx.x] = f2b(tile[threadIdx.x][i]);
}

// ---------------- V transpose: QKV V-slice -> Vt[s*16+h][64][Lpad]; covers FULL Lpad ----------------
__global__ __launch_bounds__(256) void transpose_v(const short* __restrict__ QKV,
                                                   short* __restrict__ Vt,
                                                   int L, int Lpad) {
  __shared__ short tile[32][33];
  int sh = blockIdx.z;           // s*16 + h
  int s = sh >> 4, h = sh & 15;
  int kb = blockIdx.x * 32;      // key block (covers Lpad)
  int cb = blockIdx.y * 32;      // col block (0 or 32)
  int tx = threadIdx.x;
  for (int i = threadIdx.y; i < 32; i += 8) {
    int key = kb + i;
    if (key > L - 1) key = L - 1;
    tile[i][tx] = QKV[(size_t)(s * L + key) * 3072 + 2048 + h * 64 + cb + tx];
  }
  __syncthreads();
  for (int i = threadIdx.y; i < 32; i += 8)
    Vt[((size_t)sh * 64 + cb + i) * Lpad + kb + tx] = tile[tx][i];
}

// ---------------- GEMM v2: global_load_lds staging, linear [128][32] LDS, 2-barrier K-loop ----------------
__global__ __launch_bounds__(256) void gemm_bt2(const short* __restrict__ A,
                                                const short* __restrict__ BT,
                                                short* __restrict__ C,
                                                int K, int N) {
  __shared__ short As[128 * 32];
  __shared__ short Bs[128 * 32];
  const int tid = threadIdx.x;
  const int lane = tid & 63;
  const int w = tid >> 6;
  const int wr = (w >> 1) * 64, wc = (w & 1) * 64;
  const int m0 = blockIdx.y * 128;
  const int n0 = blockIdx.x * 128;
  const int l15 = lane & 15, lhi = lane >> 4;

  f32x4 acc[4][4] = {};

  for (int k0 = 0; k0 < K; k0 += 32) {
    __syncthreads();
#pragma unroll
    for (int p = 0; p < 2; ++p) {
      int g = w * 128 + p * 64 + lane;   // 0..511; LDS dest = uniform base + lane*16B
      int row = g >> 2;                  // 0..127
      int cs = (g & 3) * 8;              // col in shorts (GEMM [128][32] mapping)
      gl_lds16(A + (size_t)(m0 + row) * K + k0 + cs, &As[g * 8]);
      gl_lds16(BT + (size_t)(n0 + row) * K + k0 + cs, &Bs[g * 8]);
    }
    __syncthreads();
    s16x8 af[4], bf[4];
#pragma unroll
    for (int m = 0; m < 4; ++m)
      af[m] = *(const s16x8*)(&As[(wr + m * 16 + l15) * 32 + lhi * 8]);
#pragma unroll
    for (int n = 0; n < 4; ++n)
      bf[n] = *(const s16x8*)(&Bs[(wc + n * 16 + l15) * 32 + lhi * 8]);
#pragma unroll
    for (int m = 0; m < 4; ++m)
#pragma unroll
      for (int n = 0; n < 4; ++n)
        acc[m][n] = __builtin_amdgcn_mfma_f32_16x16x32_bf16(af[m], bf[n], acc[m][n], 0, 0, 0);
  }
#pragma unroll
  for (int m = 0; m < 4; ++m) {
    int row_base = m0 + wr + m * 16 + lhi * 4;
#pragma unroll
    for (int n = 0; n < 4; ++n) {
      int col = n0 + wc + n * 16 + l15;
#pragma unroll
      for (int r = 0; r < 4; ++r)
        C[(size_t)(row_base + r) * N + col] = f2b(acc[m][n][r]);
    }
  }
}

// ---------------- RMSNorm on Q (with 1/8 scale) and K slices of QKV, in place ----------------
__global__ __launch_bounds__(256) void rmsnorm_qk(short* __restrict__ QKV,
                                                  const float* __restrict__ g) {
  int row = blockIdx.x;
  int which = blockIdx.y;  // 0 = q, 1 = k
  size_t base = (size_t)row * 3072 + (size_t)which * 1024;
  int t = threadIdx.x;
  s16x4 in = *(const s16x4*)(QKV + base + t * 4);
  float v[4];
  float ss = 0.f;
#pragma unroll
  for (int j = 0; j < 4; ++j) {
    v[j] = b2f(in[j]);
    ss += v[j] * v[j];
  }
#pragma unroll
  for (int m = 32; m >= 1; m >>= 1) ss += __shfl_xor(ss, m);
  __shared__ float red[4];
  if ((t & 63) == 0) red[t >> 6] = ss;
  __syncthreads();
  float tot = red[0] + red[1] + red[2] + red[3];
  float inv = rsqrtf(tot * (1.0f / 1024.0f) + 1e-6f);
  if (which == 0) inv *= 0.125f;  // fold 1/sqrt(hd)
  s16x4 out;
#pragma unroll
  for (int j = 0; j < 4; ++j) out[j] = f2b(v[j] * inv * g[t * 4 + j]);
  *(s16x4*)(&QKV[base + t * 4]) = out;
}

// ---------------- causal flash attention v3 (used for local; global fallback) ----------------
// P = exp(S - 8): shift-invariant softmax with a fixed shift; masked -> exp(-1e30)=0 exactly.
// ATTN chunk mapping is [64 rows][64 shorts]: kr = g>>3 (0..63), cs = (g&7)*8 (0..56).
__global__ __launch_bounds__(256) void attn_causal3(const short* __restrict__ QKV,  // R x 3072
                                                    const short* __restrict__ Vt,   // [s*16+h][64][Lpad]
                                                    short* __restrict__ Y,          // R x 1024
                                                    int L, int Lpad) {
  const int h = blockIdx.y, s = blockIdx.z;
  const int q0 = blockIdx.x * 64;
  const int tid = threadIdx.x;
  const int lane = tid & 63, w = tid >> 6;
  const int l15 = lane & 15, lhi = lane >> 4;
  const int row0 = s * L;

  __shared__ short Ks[64][72];
  __shared__ short Vs[2][64][72];
  __shared__ short Ps[4][16][72];

  int qld = q0 + w * 16 + l15;
  if (qld > L - 1) qld = L - 1;
  const size_t qrow = (size_t)(row0 + qld) * 3072 + h * 64;
  s16x8 qf0 = *(const s16x8*)(QKV + qrow + lhi * 8);
  s16x8 qf1 = *(const s16x8*)(QKV + qrow + 32 + lhi * 8);

  float lsum[4] = {0.f, 0.f, 0.f, 0.f};
  f32x4 o[4];
#pragma unroll
  for (int d = 0; d < 4; ++d) o[d] = f32x4{0.f, 0.f, 0.f, 0.f};

  const short* Vbase = Vt + (size_t)(s * 16 + h) * 64 * Lpad;

  s16x8 kreg[2], vreg[2];
#pragma unroll
  for (int p = 0; p < 2; ++p) {
    int g = tid + p * 256;
    int kr = g >> 3, cs = (g & 7) * 8;
    int krow = kr;
    if (krow > L - 1) krow = L - 1;
    kreg[p] = *(const s16x8*)(QKV + (size_t)(row0 + krow) * 3072 + 1024 + h * 64 + cs);
    vreg[p] = *(const s16x8*)(Vbase + (size_t)kr * Lpad + cs);
  }

  int buf = 0;
  for (int kb = 0; kb <= q0; kb += 64, buf ^= 1) {
#pragma unroll
    for (int p = 0; p < 2; ++p) {
      int g = tid + p * 256;
      int kr = g >> 3, cs = (g & 7) * 8;
      *(s16x8*)(&Ks[kr][cs]) = kreg[p];
      *(s16x8*)(&Vs[buf][kr][cs]) = vreg[p];
    }
    if (kb + 64 <= q0) {
#pragma unroll
      for (int p = 0; p < 2; ++p) {
        int g = tid + p * 256;
        int kr = g >> 3, cs = (g & 7) * 8;
        int krow = kb + 64 + kr;
        if (krow > L - 1) krow = L - 1;
        kreg[p] = *(const s16x8*)(QKV + (size_t)(row0 + krow) * 3072 + 1024 + h * 64 + cs);
        vreg[p] = *(const s16x8*)(Vbase + (size_t)kr * Lpad + kb + 64 + cs);
      }
    }
    __syncthreads();

    f32x4 st[4];
#pragma unroll
    for (int n = 0; n < 4; ++n) {
      s16x8 k0 = *(const s16x8*)(&Ks[n * 16 + l15][lhi * 8]);
      s16x8 k1 = *(const s16x8*)(&Ks[n * 16 + l15][32 + lhi * 8]);
      f32x4 sa = f32x4{0.f, 0.f, 0.f, 0.f};
      sa = __builtin_amdgcn_mfma_f32_16x16x32_bf16(qf0, k0, sa, 0, 0, 0);
      sa = __builtin_amdgcn_mfma_f32_16x16x32_bf16(qf1, k1, sa, 0, 0, 0);
      st[n] = sa;
    }

    if (kb == q0) {
#pragma unroll
      for (int n = 0; n < 4; ++n) {
        int key = kb + n * 16 + l15;
#pragma unroll
        for (int r = 0; r < 4; ++r) {
          int qr = q0 + w * 16 + lhi * 4 + r;
          if (key > qr) st[n][r] = -1e30f;
        }
      }
    }

#pragma unroll
    for (int n = 0; n < 4; ++n) {
#pragma unroll
      for (int r = 0; r < 4; ++r) {
        float p = __expf(st[n][r] - 8.0f);
        Ps[w][lhi * 4 + r][n * 16 + l15] = f2b(p);
        lsum[r] += p;
      }
    }
    __syncthreads();

#pragma unroll
    for (int kk = 0; kk < 2; ++kk) {
      s16x8 pa = *(const s16x8*)(&Ps[w][l15][kk * 32 + lhi * 8]);
#pragma unroll
      for (int d = 0; d < 4; ++d) {
        s16x8 vf = *(const s16x8*)(&Vs[buf][d * 16 + l15][kk * 32 + lhi * 8]);
        o[d] = __builtin_amdgcn_mfma_f32_16x16x32_bf16(pa, vf, o[d], 0, 0, 0);
      }
    }
  }

#pragma unroll
  for (int r = 0; r < 4; ++r) {
#pragma unroll
    for (int mm = 1; mm <= 8; mm <<= 1) lsum[r] += __shfl_xor(lsum[r], mm, 16);
  }
#pragma unroll
  for (int d = 0; d < 4; ++d) {
#pragma unroll
    for (int r = 0; r < 4; ++r) {
      int qr = q0 + w * 16 + lhi * 4 + r;
      if (qr < L)
        Y[(size_t)(row0 + qr) * 1024 + h * 64 + d * 16 + l15] = f2b(o[d][r] / lsum[r]);
    }
  }
}

// ---------------- split-K causal attention (global, L=2064) ----------------
// Fixed-shift softmax => partial (o, lsum) over disjoint key chunks combine by ADDITION.
// Workgroup = (q-block qb, key-chunk of CT tiles). Partials accumulated via f32 atomics
// into o_acc[sh][row][col] / ls_acc[sh][row] (pre-zeroed). Longest chain: CT iters (vs 33).
__global__ __launch_bounds__(256) void attn_split(const short* __restrict__ QKV,
                                                  const short* __restrict__ Vt,
                                                  float* __restrict__ o_acc,
                                                  float* __restrict__ ls_acc) {
  const int qb = blockIdx.x;       // 0..32
  const int chunk = blockIdx.y;    // 0..4
  const int sh = blockIdx.z;       // s*16+h
  const int t0 = chunk * CT;
  if (t0 > qb) return;             // empty chunk for short q-blocks
  const int t1 = min(t0 + CT, qb + 1);
  const int h = sh & 15, s = sh >> 4;
  const int q0 = qb * 64;
  const int tid = threadIdx.x;
  const int lane = tid & 63, w = tid >> 6;
  const int l15 = lane & 15, lhi = lane >> 4;
  const int row0 = s * LG;
  const int Lpad = 2112;

  __shared__ short Ks[64][72];
  __shared__ short Vs[2][64][72];
  __shared__ short Ps[4][16][72];

  int qld = q0 + w * 16 + l15;
  if (qld > LG - 1) qld = LG - 1;
  const size_t qrow = (size_t)(row0 + qld) * 3072 + h * 64;
  s16x8 qf0 = *(const s16x8*)(QKV + qrow + lhi * 8);
  s16x8 qf1 = *(const s16x8*)(QKV + qrow + 32 + lhi * 8);

  float lsum[4] = {0.f, 0.f, 0.f, 0.f};
  f32x4 o[4];
#pragma unroll
  for (int d = 0; d < 4; ++d) o[d] = f32x4{0.f, 0.f, 0.f, 0.f};

  const short* Vbase = Vt + (size_t)sh * 64 * Lpad;

  s16x8 kreg[2], vreg[2];
  const int kb0 = t0 * 64;
#pragma unroll
  for (int p = 0; p < 2; ++p) {
    int g = tid + p * 256;
    int kr = g >> 3, cs = (g & 7) * 8;
    int krow = kb0 + kr;
    if (krow > LG - 1) krow = LG - 1;
    kreg[p] = *(const s16x8*)(QKV + (size_t)(row0 + krow) * 3072 + 1024 + h * 64 + cs);
    vreg[p] = *(const s16x8*)(Vbase + (size_t)kr * Lpad + kb0 + cs);
  }

  int buf = 0;
  for (int t = t0; t < t1; ++t, buf ^= 1) {
    const int kb = t * 64;
#pragma unroll
    for (int p = 0; p < 2; ++p) {
      int g = tid + p * 256;
      int kr = g >> 3, cs = (g & 7) * 8;
      *(s16x8*)(&Ks[kr][cs]) = kreg[p];
      *(s16x8*)(&Vs[buf][kr][cs]) = vreg[p];
    }
    if (t + 1 < t1) {
#pragma unroll
      for (int p = 0; p < 2; ++p) {
        int g = tid + p * 256;
        int kr = g >> 3, cs = (g & 7) * 8;
        int krow = kb + 64 + kr;
        if (krow > LG - 1) krow = LG - 1;
        kreg[p] = *(const s16x8*)(QKV + (size_t)(row0 + krow) * 3072 + 1024 + h * 64 + cs);
        vreg[p] = *(const s16x8*)(Vbase + (size_t)kr * Lpad + kb + 64 + cs);
      }
    }
    __syncthreads();

    f32x4 st[4];
#pragma unroll
    for (int n = 0; n < 4; ++n) {
      s16x8 k0 = *(const s16x8*)(&Ks[n * 16 + l15][lhi * 8]);
      s16x8 k1 = *(const s16x8*)(&Ks[n * 16 + l15][32 + lhi * 8]);
      f32x4 sa = f32x4{0.f, 0.f, 0.f, 0.f};
      sa = __builtin_amdgcn_mfma_f32_16x16x32_bf16(qf0, k0, sa, 0, 0, 0);
      sa = __builtin_amdgcn_mfma_f32_16x16x32_bf16(qf1, k1, sa, 0, 0, 0);
      st[n] = sa;
    }

    if (t == qb) {  // causal mask only on the diagonal tile
#pragma unroll
      for (int n = 0; n < 4; ++n) {
        int key = kb + n * 16 + l15;
#pragma unroll
        for (int r = 0; r < 4; ++r) {
          int qr = q0 + w * 16 + lhi * 4 + r;
          if (key > qr) st[n][r] = -1e30f;
        }
      }
    }

#pragma unroll
    for (int n = 0; n < 4; ++n) {
#pragma unroll
      for (int r = 0; r < 4; ++r) {
        float p = __expf(st[n][r] - 8.0f);
        Ps[w][lhi * 4 + r][n * 16 + l15] = f2b(p);
        lsum[r] += p;
      }
    }
    __syncthreads();

#pragma unroll
    for (int kk = 0; kk < 2; ++kk) {
      s16x8 pa = *(const s16x8*)(&Ps[w][l15][kk * 32 + lhi * 8]);
#pragma unroll
      for (int d = 0; d < 4; ++d) {
        s16x8 vf = *(const s16x8*)(&Vs[buf][d * 16 + l15][kk * 32 + lhi * 8]);
        o[d] = __builtin_amdgcn_mfma_f32_16x16x32_bf16(pa, vf, o[d], 0, 0, 0);
      }
    }
  }

  // reduce lsum over the 16-lane column group, then atomically accumulate partials
#pragma unroll
  for (int r = 0; r < 4; ++r) {
#pragma unroll
    for (int mm = 1; mm <= 8; mm <<= 1) lsum[r] += __shfl_xor(lsum[r], mm, 16);
  }
#pragma unroll
  for (int r = 0; r < 4; ++r) {
    int qr = q0 + w * 16 + lhi * 4 + r;
    if (qr < LG) {
      if (l15 == 0) atomicAdd(&ls_acc[(size_t)sh * LG + qr], lsum[r]);
#pragma unroll
      for (int d = 0; d < 4; ++d)
        atomicAdd(&o_acc[((size_t)sh * LG + qr) * 64 + d * 16 + l15], o[d][r]);
    }
  }
}

// merge: Y = o_acc / ls_acc  (block = 4 rows x 64 cols)
__global__ __launch_bounds__(256) void attn_merge(const float* __restrict__ o_acc,
                                                  const float* __restrict__ ls_acc,
                                                  short* __restrict__ Y) {
  int sh = blockIdx.z * 16 + blockIdx.y;
  int s = sh >> 4, h = sh & 15;
  int row = blockIdx.x * 4 + (threadIdx.x >> 6);
  int col = threadIdx.x & 63;
  if (row < LG) {
    float inv = 1.0f / ls_acc[(size_t)sh * LG + row];
    float v = o_acc[((size_t)sh * LG + row) * 64 + col];
    Y[(size_t)(s * LG + row) * 1024 + h * 64 + col] = f2b(v * inv);
  }
}

// ---------------- gather/scatter helpers ----------------
__global__ __launch_bounds__(256) void build_xl(const float* __restrict__ x,
                                                const float* __restrict__ lm,
                                                short* __restrict__ Xin) {
  int row = blockIdx.x;  // 0..4351 (exact, no pads)
  int s = row / 272, r = row % 272;
  const float* src = (r < 16) ? lm + ((size_t)s * 16 + r) * 1024
                              : x + ((size_t)s * 256 + (r - 16)) * 1024;
  int t = threadIdx.x;
  f32x4 v = *(const f32x4*)(src + t * 4);
  s16x4 o;
#pragma unroll
  for (int j = 0; j < 4; ++j) o[j] = f2b(v[j]);
  *(s16x4*)(&Xin[(size_t)row * 1024 + t * 4]) = o;
}

__global__ __launch_bounds__(256) void build_xg(const float* __restrict__ x,
                                                const float* __restrict__ mem,
                                                short* __restrict__ Xin) {
  int row = blockIdx.x;            // 0..4351: writes ALL MPAD rows (pads clamp source)
  int sr = row < 4128 ? row : 4127;
  int b = sr / 2064, r = sr % 2064;
  const float* src = (r < 16) ? mem + ((size_t)b * 16 + r) * 1024
                              : x + ((size_t)b * 2048 + (r - 16)) * 1024;
  int t = threadIdx.x;
  f32x4 v = *(const f32x4*)(src + t * 4);
  s16x4 o;
#pragma unroll
  for (int j = 0; j < 4; ++j) o[j] = f2b(v[j]);
  *(s16x4*)(&Xin[(size_t)row * 1024 + t * 4]) = o;
}

__global__ __launch_bounds__(256) void split_local(const short* __restrict__ Pout,
                                                   float* __restrict__ x,
                                                   float* __restrict__ lm) {
  int row = blockIdx.x;  // 0..4351
  int s = row / 272, r = row % 272;
  int t = threadIdx.x;
  s16x4 v = *(const s16x4*)(Pout + (size_t)row * 1024 + t * 4);
  float* dst = (r < 16) ? lm + ((size_t)s * 16 + r) * 1024
                        : x + ((size_t)s * 256 + (r - 16)) * 1024;
  f32x4 o;
#pragma unroll
  for (int j = 0; j < 4; ++j) o[j] = b2f(v[j]);
  *(f32x4*)(dst + t * 4) = o;
}

__global__ __launch_bounds__(256) void split_global(const short* __restrict__ Pout,
                                                    float* __restrict__ x,
                                                    float* __restrict__ mem) {
  int row = blockIdx.x;  // 0..4127
  int b = row / 2064, r = row % 2064;
  int t = threadIdx.x;
  s16x4 v = *(const s16x4*)(Pout + (size_t)row * 1024 + t * 4);
  float* dst = (r < 16) ? mem + ((size_t)b * 16 + r) * 1024
                        : x + ((size_t)b * 2048 + (r - 16)) * 1024;
  f32x4 o;
#pragma unroll
  for (int j = 0; j < 4; ++j) o[j] = b2f(v[j]);
  *(f32x4*)(dst + t * 4) = o;
}

// ---------------- orchestration ----------------
extern "C" void kernel_launch(void* const* d_in, const int* in_sizes, int n_in,
                              void* d_out, int out_size, void* d_ws, size_t ws_size,
                              hipStream_t stream) {
  const float* x_in = (const float*)d_in[0];
  const float* mem_in = (const float*)d_in[1];
  const float* lm_in = (const float*)d_in[2];
  const float* Wqkv_loc = (const float*)d_in[3];
  const float* Wproj_loc = (const float*)d_in[4];
  const float* g_loc = (const float*)d_in[5];
  const float* Wqkv_glob = (const float*)d_in[6];
  const float* Wproj_glob = (const float*)d_in[7];
  const float* g_glob = (const float*)d_in[8];

  char* ws = (char*)d_ws;
  size_t off = 0;
  auto alloc = [&](size_t bytes) {
    char* p = ws + off;
    off += (bytes + 255) & ~(size_t)255;
    return p;
  };
  short* Wt = (short*)alloc((size_t)3072 * 1024 * 2);          // 6.29 MB
  float* x_cur = (float*)alloc((size_t)4096 * 1024 * 4);       // 16.78 MB
  float* lm_cur = (float*)alloc((size_t)256 * 1024 * 4);       // 1.05 MB
  float* mem_cur = (float*)alloc((size_t)32 * 1024 * 4);       // 0.13 MB
  short* Xin = (short*)alloc((size_t)MPAD * 1024 * 2);         // 8.91 MB
  short* QKVb = (short*)alloc((size_t)MPAD * 3072 * 2);        // 26.74 MB
  short* Yb = (short*)alloc((size_t)MPAD * 1024 * 2);          // 8.91 MB
  short* Pout = (short*)alloc((size_t)MPAD * 1024 * 2);        // 8.91 MB
  short* Vtb = (short*)alloc((size_t)256 * 64 * 320 * 2);      // 10.49 MB (max of local/global)
  size_t oacc_bytes = (size_t)32 * LG * 64 * 4;                // 16.9 MB
  size_t lacc_bytes = (size_t)32 * LG * 4;                     // 0.26 MB
  float* o_acc = (float*)alloc(oacc_bytes);
  float* ls_acc = (float*)alloc(lacc_bytes);
  const bool use_split = (ws_size >= off);  // fall back if scratch is short

  hipMemcpyAsync(x_cur, x_in, (size_t)4096 * 1024 * 4, hipMemcpyDeviceToDevice, stream);
  hipMemcpyAsync(lm_cur, lm_in, (size_t)256 * 1024 * 4, hipMemcpyDeviceToDevice, stream);
  hipMemcpyAsync(mem_cur, mem_in, (size_t)32 * 1024 * 4, hipMemcpyDeviceToDevice, stream);

  for (int i = 0; i < 2; ++i) {
    // ---- local attention over 16 sequences of L=272 (rows = 4352 = MPAD exactly) ----
    transpose_cast<<<dim3(96, 32), dim3(32, 8), 0, stream>>>(
        Wqkv_loc + (size_t)i * 1024 * 3072, Wt, 1024, 3072);
    build_xl<<<4352, 256, 0, stream>>>(x_cur, lm_cur, Xin);
    gemm_bt2<<<dim3(24, 34), 256, 0, stream>>>(Xin, Wt, QKVb, 1024, 3072);
    rmsnorm_qk<<<dim3(4352, 2), 256, 0, stream>>>(QKVb, g_loc + (size_t)i * 1024);
    transpose_v<<<dim3(10, 2, 256), dim3(32, 8), 0, stream>>>(QKVb, Vtb, 272, 320);
    attn_causal3<<<dim3(5, 16, 16), 256, 0, stream>>>(QKVb, Vtb, Yb, 272, 320);
    transpose_cast<<<dim3(32, 32), dim3(32, 8), 0, stream>>>(
        Wproj_loc + (size_t)i * 1024 * 1024, Wt, 1024, 1024);
    gemm_bt2<<<dim3(8, 34), 256, 0, stream>>>(Yb, Wt, Pout, 1024, 1024);
    split_local<<<4352, 256, 0, stream>>>(Pout, x_cur, lm_cur);

    // ---- global attention over 2 sequences of L=2064 (rows = 4128; pads deterministic) ----
    transpose_cast<<<dim3(96, 32), dim3(32, 8), 0, stream>>>(
        Wqkv_glob + (size_t)i * 1024 * 3072, Wt, 1024, 3072);
    build_xg<<<4352, 256, 0, stream>>>(x_cur, mem_cur, Xin);
    gemm_bt2<<<dim3(24, 34), 256, 0, stream>>>(Xin, Wt, QKVb, 1024, 3072);
    rmsnorm_qk<<<dim3(4128, 2), 256, 0, stream>>>(QKVb, g_glob + (size_t)i * 1024);
    transpose_v<<<dim3(66, 2, 32), dim3(32, 8), 0, stream>>>(QKVb, Vtb, 2064, 2112);
    if (use_split) {
      hipMemsetAsync(o_acc, 0, oacc_bytes, stream);
      hipMemsetAsync(ls_acc, 0, lacc_bytes, stream);
      attn_split<<<dim3(33, 5, 32), 256, 0, stream>>>(QKVb, Vtb, o_acc, ls_acc);
      attn_merge<<<dim3(516, 16, 2), 256, 0, stream>>>(o_acc, ls_acc, Yb);
    } else {
      attn_causal3<<<dim3(33, 16, 2), 256, 0, stream>>>(QKVb, Vtb, Yb, 2064, 2112);
    }
    transpose_cast<<<dim3(32, 32), dim3(32, 8), 0, stream>>>(
        Wproj_glob + (size_t)i * 1024 * 1024, Wt, 1024, 1024);
    gemm_bt2<<<dim3(8, 34), 256, 0, stream>>>(Yb, Wt, Pout, 1024, 1024);
    split_global<<<4128, 256, 0, stream>>>(Pout, x_cur, mem_cur);
  }

  hipMemcpyAsync(d_out, x_cur, (size_t)4096 * 1024 * 4, hipMemcpyDeviceToDevice, stream);
}

// Round 8
// 605.804 us; speedup vs baseline: 1.0825x; 1.0825x over previous
//
#include <hip/hip_runtime.h>
#include <hip/hip_bf16.h>
#include <math.h>

typedef __attribute__((ext_vector_type(8))) short s16x8;
typedef __attribute__((ext_vector_type(4))) short s16x4;
typedef __attribute__((ext_vector_type(4))) float f32x4;

#define MPAD 4352   // = 34*128
#define LG 2064     // global seq length
#define CT 8        // k-tiles (of 64 keys) per split chunk
#define SM_SHIFT 11.5415603f  // 8 * log2(e); softmax uses exp2(S*log2e - this)

__device__ __forceinline__ short f2b(float f) {
  unsigned u = __float_as_uint(f);
  unsigned r = (u + 0x7fffu + ((u >> 16) & 1u)) >> 16;
  return (short)(unsigned short)r;
}
__device__ __forceinline__ float b2f(short s) {
  return __uint_as_float(((unsigned)(unsigned short)s) << 16);
}

// global->LDS direct async copy, 16B per lane. LDS dest must be uniform-base + lane*16.
__device__ __forceinline__ void gl_lds16(const short* g, short* l) {
  __builtin_amdgcn_global_load_lds((const __attribute__((address_space(1))) short*)g,
                                   (__attribute__((address_space(3))) short*)l, 16, 0, 0);
}

// ---------------- transpose + cast: in f32 (K x N) -> out bf16 (N x K) ----------------
__global__ __launch_bounds__(256) void transpose_cast(const float* __restrict__ in,
                                                      short* __restrict__ out,
                                                      int K, int N) {
  __shared__ float tile[32][33];
  int bn = blockIdx.x * 32;
  int bk = blockIdx.y * 32;
  for (int i = threadIdx.y; i < 32; i += 8)
    tile[i][threadIdx.x] = in[(size_t)(bk + i) * N + bn + threadIdx.x];
  __syncthreads();
  for (int i = threadIdx.y; i < 32; i += 8)
    out[(size_t)(bn + i) * K + bk + threadIdx.x] = f2b(tile[threadIdx.x][i]);
}

// ---------------- V transpose: QKV V-slice -> Vt[s*16+h][64][Lpad]; covers FULL Lpad ----------------
__global__ __launch_bounds__(256) void transpose_v(const short* __restrict__ QKV,
                                                   short* __restrict__ Vt,
                                                   int L, int Lpad) {
  __shared__ short tile[32][33];
  int sh = blockIdx.z;
  int s = sh >> 4, h = sh & 15;
  int kb = blockIdx.x * 32;
  int cb = blockIdx.y * 32;
  int tx = threadIdx.x;
  for (int i = threadIdx.y; i < 32; i += 8) {
    int key = kb + i;
    if (key > L - 1) key = L - 1;
    tile[i][tx] = QKV[(size_t)(s * L + key) * 3072 + 2048 + h * 64 + cb + tx];
  }
  __syncthreads();
  for (int i = threadIdx.y; i < 32; i += 8)
    Vt[((size_t)sh * 64 + cb + i) * Lpad + kb + tx] = tile[tx][i];
}

// ---------------- GEMM v3: 2-phase prefetch (T3-minimum), gl_lds dbuf, 1 barrier/iter ----------------
// Issue STAGE(t+1) into buf^1 BEFORE computing tile t from buf; __syncthreads() at iter end
// (compiler emits vmcnt(0)+barrier) so the t+1 loads' latency overlaps this tile's compute.
__global__ __launch_bounds__(256) void gemm_bt3(const short* __restrict__ A,
                                                const short* __restrict__ BT,
                                                short* __restrict__ C,
                                                int K, int N) {
  __shared__ short As[2][128 * 32];
  __shared__ short Bs[2][128 * 32];
  const int tid = threadIdx.x;
  const int lane = tid & 63;
  const int w = tid >> 6;
  const int wr = (w >> 1) * 64, wc = (w & 1) * 64;
  const int m0 = blockIdx.y * 128;
  const int n0 = blockIdx.x * 128;
  const int l15 = lane & 15, lhi = lane >> 4;

  f32x4 acc[4][4] = {};

  auto STAGE = [&](int b, int k0) {
#pragma unroll
    for (int p = 0; p < 2; ++p) {
      int g = w * 128 + p * 64 + lane;   // 0..511; LDS dest = uniform base + lane*16B
      int row = g >> 2;                  // 0..127
      int cs = (g & 3) * 8;              // col in shorts ([128][32] mapping)
      gl_lds16(A + (size_t)(m0 + row) * K + k0 + cs, &As[b][g * 8]);
      gl_lds16(BT + (size_t)(n0 + row) * K + k0 + cs, &Bs[b][g * 8]);
    }
  };

  const int nt = K >> 5;
  STAGE(0, 0);
  __syncthreads();  // prologue loads landed
  int cur = 0;
  for (int t = 0; t < nt; ++t) {
    if (t + 1 < nt) STAGE(cur ^ 1, (t + 1) << 5);  // prefetch next tile (overlaps compute)
    s16x8 af[4], bf[4];
#pragma unroll
    for (int m = 0; m < 4; ++m)
      af[m] = *(const s16x8*)(&As[cur][(wr + m * 16 + l15) * 32 + lhi * 8]);
#pragma unroll
    for (int n = 0; n < 4; ++n)
      bf[n] = *(const s16x8*)(&Bs[cur][(wc + n * 16 + l15) * 32 + lhi * 8]);
#pragma unroll
    for (int m = 0; m < 4; ++m)
#pragma unroll
      for (int n = 0; n < 4; ++n)
        acc[m][n] = __builtin_amdgcn_mfma_f32_16x16x32_bf16(af[m], bf[n], acc[m][n], 0, 0, 0);
    __syncthreads();  // drains prefetch vmcnt + protects buf reuse
    cur ^= 1;
  }
#pragma unroll
  for (int m = 0; m < 4; ++m) {
    int row_base = m0 + wr + m * 16 + lhi * 4;
#pragma unroll
    for (int n = 0; n < 4; ++n) {
      int col = n0 + wc + n * 16 + l15;
#pragma unroll
      for (int r = 0; r < 4; ++r)
        C[(size_t)(row_base + r) * N + col] = f2b(acc[m][n][r]);
    }
  }
}

// ---------------- RMSNorm on Q (with 1/8*log2e scale) and K slices of QKV, in place ----------------
__global__ __launch_bounds__(256) void rmsnorm_qk(short* __restrict__ QKV,
                                                  const float* __restrict__ g) {
  int row = blockIdx.x;
  int which = blockIdx.y;  // 0 = q, 1 = k
  size_t base = (size_t)row * 3072 + (size_t)which * 1024;
  int t = threadIdx.x;
  s16x4 in = *(const s16x4*)(QKV + base + t * 4);
  float v[4];
  float ss = 0.f;
#pragma unroll
  for (int j = 0; j < 4; ++j) {
    v[j] = b2f(in[j]);
    ss += v[j] * v[j];
  }
#pragma unroll
  for (int m = 32; m >= 1; m >>= 1) ss += __shfl_xor(ss, m);
  __shared__ float red[4];
  if ((t & 63) == 0) red[t >> 6] = ss;
  __syncthreads();
  float tot = red[0] + red[1] + red[2] + red[3];
  float inv = rsqrtf(tot * (1.0f / 1024.0f) + 1e-6f);
  if (which == 0) inv *= 0.125f * 1.44269504f;  // fold 1/sqrt(hd) AND log2(e) into Q
  s16x4 out;
#pragma unroll
  for (int j = 0; j < 4; ++j) out[j] = f2b(v[j] * inv * g[t * 4 + j]);
  *(s16x4*)(&QKV[base + t * 4]) = out;
}

// ---------------- causal flash attention (local + global fallback) ----------------
// P = exp2(S_log2 - SM_SHIFT), with log2(e) pre-folded into Q. Masked -> exp2(-1e30)=0.
__global__ __launch_bounds__(256) void attn_causal3(const short* __restrict__ QKV,
                                                    const short* __restrict__ Vt,
                                                    short* __restrict__ Y,
                                                    int L, int Lpad) {
  const int h = blockIdx.y, s = blockIdx.z;
  const int q0 = blockIdx.x * 64;
  const int tid = threadIdx.x;
  const int lane = tid & 63, w = tid >> 6;
  const int l15 = lane & 15, lhi = lane >> 4;
  const int row0 = s * L;

  __shared__ short Ks[64][72];
  __shared__ short Vs[2][64][72];
  __shared__ short Ps[4][16][72];

  int qld = q0 + w * 16 + l15;
  if (qld > L - 1) qld = L - 1;
  const size_t qrow = (size_t)(row0 + qld) * 3072 + h * 64;
  s16x8 qf0 = *(const s16x8*)(QKV + qrow + lhi * 8);
  s16x8 qf1 = *(const s16x8*)(QKV + qrow + 32 + lhi * 8);

  float lsum[4] = {0.f, 0.f, 0.f, 0.f};
  f32x4 o[4];
#pragma unroll
  for (int d = 0; d < 4; ++d) o[d] = f32x4{0.f, 0.f, 0.f, 0.f};

  const short* Vbase = Vt + (size_t)(s * 16 + h) * 64 * Lpad;

  s16x8 kreg[2], vreg[2];
#pragma unroll
  for (int p = 0; p < 2; ++p) {
    int g = tid + p * 256;
    int kr = g >> 3, cs = (g & 7) * 8;
    int krow = kr;
    if (krow > L - 1) krow = L - 1;
    kreg[p] = *(const s16x8*)(QKV + (size_t)(row0 + krow) * 3072 + 1024 + h * 64 + cs);
    vreg[p] = *(const s16x8*)(Vbase + (size_t)kr * Lpad + cs);
  }

  int buf = 0;
  for (int kb = 0; kb <= q0; kb += 64, buf ^= 1) {
#pragma unroll
    for (int p = 0; p < 2; ++p) {
      int g = tid + p * 256;
      int kr = g >> 3, cs = (g & 7) * 8;
      *(s16x8*)(&Ks[kr][cs]) = kreg[p];
      *(s16x8*)(&Vs[buf][kr][cs]) = vreg[p];
    }
    if (kb + 64 <= q0) {
#pragma unroll
      for (int p = 0; p < 2; ++p) {
        int g = tid + p * 256;
        int kr = g >> 3, cs = (g & 7) * 8;
        int krow = kb + 64 + kr;
        if (krow > L - 1) krow = L - 1;
        kreg[p] = *(const s16x8*)(QKV + (size_t)(row0 + krow) * 3072 + 1024 + h * 64 + cs);
        vreg[p] = *(const s16x8*)(Vbase + (size_t)kr * Lpad + kb + 64 + cs);
      }
    }
    __syncthreads();

    f32x4 st[4];
#pragma unroll
    for (int n = 0; n < 4; ++n) {
      s16x8 k0 = *(const s16x8*)(&Ks[n * 16 + l15][lhi * 8]);
      s16x8 k1 = *(const s16x8*)(&Ks[n * 16 + l15][32 + lhi * 8]);
      f32x4 sa = f32x4{0.f, 0.f, 0.f, 0.f};
      sa = __builtin_amdgcn_mfma_f32_16x16x32_bf16(qf0, k0, sa, 0, 0, 0);
      sa = __builtin_amdgcn_mfma_f32_16x16x32_bf16(qf1, k1, sa, 0, 0, 0);
      st[n] = sa;
    }

    if (kb == q0) {
#pragma unroll
      for (int n = 0; n < 4; ++n) {
        int key = kb + n * 16 + l15;
#pragma unroll
        for (int r = 0; r < 4; ++r) {
          int qr = q0 + w * 16 + lhi * 4 + r;
          if (key > qr) st[n][r] = -1e30f;
        }
      }
    }

#pragma unroll
    for (int n = 0; n < 4; ++n) {
#pragma unroll
      for (int r = 0; r < 4; ++r) {
        float p = exp2f(st[n][r] - SM_SHIFT);
        Ps[w][lhi * 4 + r][n * 16 + l15] = f2b(p);
        lsum[r] += p;
      }
    }
    __syncthreads();

#pragma unroll
    for (int kk = 0; kk < 2; ++kk) {
      s16x8 pa = *(const s16x8*)(&Ps[w][l15][kk * 32 + lhi * 8]);
#pragma unroll
      for (int d = 0; d < 4; ++d) {
        s16x8 vf = *(const s16x8*)(&Vs[buf][d * 16 + l15][kk * 32 + lhi * 8]);
        o[d] = __builtin_amdgcn_mfma_f32_16x16x32_bf16(pa, vf, o[d], 0, 0, 0);
      }
    }
  }

#pragma unroll
  for (int r = 0; r < 4; ++r) {
#pragma unroll
    for (int mm = 1; mm <= 8; mm <<= 1) lsum[r] += __shfl_xor(lsum[r], mm, 16);
  }
#pragma unroll
  for (int d = 0; d < 4; ++d) {
#pragma unroll
    for (int r = 0; r < 4; ++r) {
      int qr = q0 + w * 16 + lhi * 4 + r;
      if (qr < L)
        Y[(size_t)(row0 + qr) * 1024 + h * 64 + d * 16 + l15] = f2b(o[d][r] / lsum[r]);
    }
  }
}

// ---------------- split-K causal attention (global, L=2064) ----------------
__global__ __launch_bounds__(256) void attn_split(const short* __restrict__ QKV,
                                                  const short* __restrict__ Vt,
                                                  float* __restrict__ o_acc,
                                                  float* __restrict__ ls_acc) {
  const int qb = blockIdx.x;
  const int chunk = blockIdx.y;
  const int sh = blockIdx.z;
  const int t0 = chunk * CT;
  if (t0 > qb) return;
  const int t1 = min(t0 + CT, qb + 1);
  const int h = sh & 15, s = sh >> 4;
  const int q0 = qb * 64;
  const int tid = threadIdx.x;
  const int lane = tid & 63, w = tid >> 6;
  const int l15 = lane & 15, lhi = lane >> 4;
  const int row0 = s * LG;
  const int Lpad = 2112;

  __shared__ short Ks[64][72];
  __shared__ short Vs[2][64][72];
  __shared__ short Ps[4][16][72];

  int qld = q0 + w * 16 + l15;
  if (qld > LG - 1) qld = LG - 1;
  const size_t qrow = (size_t)(row0 + qld) * 3072 + h * 64;
  s16x8 qf0 = *(const s16x8*)(QKV + qrow + lhi * 8);
  s16x8 qf1 = *(const s16x8*)(QKV + qrow + 32 + lhi * 8);

  float lsum[4] = {0.f, 0.f, 0.f, 0.f};
  f32x4 o[4];
#pragma unroll
  for (int d = 0; d < 4; ++d) o[d] = f32x4{0.f, 0.f, 0.f, 0.f};

  const short* Vbase = Vt + (size_t)sh * 64 * Lpad;

  s16x8 kreg[2], vreg[2];
  const int kb0 = t0 * 64;
#pragma unroll
  for (int p = 0; p < 2; ++p) {
    int g = tid + p * 256;
    int kr = g >> 3, cs = (g & 7) * 8;
    int krow = kb0 + kr;
    if (krow > LG - 1) krow = LG - 1;
    kreg[p] = *(const s16x8*)(QKV + (size_t)(row0 + krow) * 3072 + 1024 + h * 64 + cs);
    vreg[p] = *(const s16x8*)(Vbase + (size_t)kr * Lpad + kb0 + cs);
  }

  int buf = 0;
  for (int t = t0; t < t1; ++t, buf ^= 1) {
    const int kb = t * 64;
#pragma unroll
    for (int p = 0; p < 2; ++p) {
      int g = tid + p * 256;
      int kr = g >> 3, cs = (g & 7) * 8;
      *(s16x8*)(&Ks[kr][cs]) = kreg[p];
      *(s16x8*)(&Vs[buf][kr][cs]) = vreg[p];
    }
    if (t + 1 < t1) {
#pragma unroll
      for (int p = 0; p < 2; ++p) {
        int g = tid + p * 256;
        int kr = g >> 3, cs = (g & 7) * 8;
        int krow = kb + 64 + kr;
        if (krow > LG - 1) krow = LG - 1;
        kreg[p] = *(const s16x8*)(QKV + (size_t)(row0 + krow) * 3072 + 1024 + h * 64 + cs);
        vreg[p] = *(const s16x8*)(Vbase + (size_t)kr * Lpad + kb + 64 + cs);
      }
    }
    __syncthreads();

    f32x4 st[4];
#pragma unroll
    for (int n = 0; n < 4; ++n) {
      s16x8 k0 = *(const s16x8*)(&Ks[n * 16 + l15][lhi * 8]);
      s16x8 k1 = *(const s16x8*)(&Ks[n * 16 + l15][32 + lhi * 8]);
      f32x4 sa = f32x4{0.f, 0.f, 0.f, 0.f};
      sa = __builtin_amdgcn_mfma_f32_16x16x32_bf16(qf0, k0, sa, 0, 0, 0);
      sa = __builtin_amdgcn_mfma_f32_16x16x32_bf16(qf1, k1, sa, 0, 0, 0);
      st[n] = sa;
    }

    if (t == qb) {
#pragma unroll
      for (int n = 0; n < 4; ++n) {
        int key = kb + n * 16 + l15;
#pragma unroll
        for (int r = 0; r < 4; ++r) {
          int qr = q0 + w * 16 + lhi * 4 + r;
          if (key > qr) st[n][r] = -1e30f;
        }
      }
    }

#pragma unroll
    for (int n = 0; n < 4; ++n) {
#pragma unroll
      for (int r = 0; r < 4; ++r) {
        float p = exp2f(st[n][r] - SM_SHIFT);
        Ps[w][lhi * 4 + r][n * 16 + l15] = f2b(p);
        lsum[r] += p;
      }
    }
    __syncthreads();

#pragma unroll
    for (int kk = 0; kk < 2; ++kk) {
      s16x8 pa = *(const s16x8*)(&Ps[w][l15][kk * 32 + lhi * 8]);
#pragma unroll
      for (int d = 0; d < 4; ++d) {
        s16x8 vf = *(const s16x8*)(&Vs[buf][d * 16 + l15][kk * 32 + lhi * 8]);
        o[d] = __builtin_amdgcn_mfma_f32_16x16x32_bf16(pa, vf, o[d], 0, 0, 0);
      }
    }
  }

#pragma unroll
  for (int r = 0; r < 4; ++r) {
#pragma unroll
    for (int mm = 1; mm <= 8; mm <<= 1) lsum[r] += __shfl_xor(lsum[r], mm, 16);
  }
#pragma unroll
  for (int r = 0; r < 4; ++r) {
    int qr = q0 + w * 16 + lhi * 4 + r;
    if (qr < LG) {
      if (l15 == 0) atomicAdd(&ls_acc[(size_t)sh * LG + qr], lsum[r]);
#pragma unroll
      for (int d = 0; d < 4; ++d)
        atomicAdd(&o_acc[((size_t)sh * LG + qr) * 64 + d * 16 + l15], o[d][r]);
    }
  }
}

// merge: Y = o_acc / ls_acc
__global__ __launch_bounds__(256) void attn_merge(const float* __restrict__ o_acc,
                                                  const float* __restrict__ ls_acc,
                                                  short* __restrict__ Y) {
  int sh = blockIdx.z * 16 + blockIdx.y;
  int s = sh >> 4, h = sh & 15;
  int row = blockIdx.x * 4 + (threadIdx.x >> 6);
  int col = threadIdx.x & 63;
  if (row < LG) {
    float inv = 1.0f / ls_acc[(size_t)sh * LG + row];
    float v = o_acc[((size_t)sh * LG + row) * 64 + col];
    Y[(size_t)(s * LG + row) * 1024 + h * 64 + col] = f2b(v * inv);
  }
}

// ---------------- fused gather/scatter ----------------
// initial local build (reads inputs directly)
__global__ __launch_bounds__(256) void build_xl(const float* __restrict__ x,
                                                const float* __restrict__ lm,
                                                short* __restrict__ Xin) {
  int row = blockIdx.x;  // 0..4351
  int s = row / 272, r = row % 272;
  const float* src = (r < 16) ? lm + ((size_t)s * 16 + r) * 1024
                              : x + ((size_t)s * 256 + (r - 16)) * 1024;
  int t = threadIdx.x;
  f32x4 v = *(const f32x4*)(src + t * 4);
  s16x4 o;
#pragma unroll
  for (int j = 0; j < 4; ++j) o[j] = f2b(v[j]);
  *(s16x4*)(&Xin[(size_t)row * 1024 + t * 4]) = o;
}

// after LOCAL proj: scatter lm_out and directly build the GLOBAL-layout Xin.
// grid 4608: rows 0..4351 = global Xin rows (pads clamp); rows 4352..4607 = 256 lm rows.
__global__ __launch_bounds__(256) void split_local_build_xg(const short* __restrict__ Pout,
                                                            const float* __restrict__ mem_src,
                                                            float* __restrict__ lm_out,
                                                            short* __restrict__ Xin) {
  int row = blockIdx.x;
  int t = threadIdx.x;
  if (row < 4352) {
    int sr = row < 4128 ? row : 4127;
    int b = sr / 2064, r = sr % 2064;
    s16x4 o;
    if (r < 16) {
      f32x4 v = *(const f32x4*)(mem_src + ((size_t)(b * 16 + r)) * 1024 + t * 4);
#pragma unroll
      for (int j = 0; j < 4; ++j) o[j] = f2b(v[j]);
    } else {
      int f = b * 2048 + (r - 16);                 // x flat row
      int pr = (f >> 8) * 272 + 16 + (f & 255);    // local Pout row
      o = *(const s16x4*)(Pout + (size_t)pr * 1024 + t * 4);
    }
    *(s16x4*)(&Xin[(size_t)row * 1024 + t * 4]) = o;
  } else {
    int m = row - 4352;                            // lm row 0..255
    int pr = (m >> 4) * 272 + (m & 15);
    s16x4 v = *(const s16x4*)(Pout + (size_t)pr * 1024 + t * 4);
    f32x4 o;
#pragma unroll
    for (int j = 0; j < 4; ++j) o[j] = b2f(v[j]);
    *(f32x4*)(&lm_out[(size_t)m * 1024 + t * 4]) = o;
  }
}

// after GLOBAL proj (i=0): scatter mem_out and directly build the LOCAL-layout Xin.
// grid 4384: rows 0..4351 = local Xin rows; rows 4352..4383 = 32 mem rows.
__global__ __launch_bounds__(256) void split_global_build_xl(const short* __restrict__ Pout,
                                                             const float* __restrict__ lm_src,
                                                             float* __restrict__ mem_out,
                                                             short* __restrict__ Xin) {
  int row = blockIdx.x;
  int t = threadIdx.x;
  if (row < 4352) {
    int s = row / 272, r = row % 272;
    s16x4 o;
    if (r < 16) {
      f32x4 v = *(const f32x4*)(lm_src + ((size_t)(s * 16 + r)) * 1024 + t * 4);
#pragma unroll
      for (int j = 0; j < 4; ++j) o[j] = f2b(v[j]);
    } else {
      int f = s * 256 + (r - 16);                    // x flat row
      int pr = (f >> 11) * 2064 + 16 + (f & 2047);   // global Pout row
      o = *(const s16x4*)(Pout + (size_t)pr * 1024 + t * 4);
    }
    *(s16x4*)(&Xin[(size_t)row * 1024 + t * 4]) = o;
  } else {
    int m = row - 4352;                              // mem row 0..31
    int pr = (m >> 4) * 2064 + (m & 15);
    s16x4 v = *(const s16x4*)(Pout + (size_t)pr * 1024 + t * 4);
    f32x4 o;
#pragma unroll
    for (int j = 0; j < 4; ++j) o[j] = b2f(v[j]);
    *(f32x4*)(&mem_out[(size_t)m * 1024 + t * 4]) = o;
  }
}

// after GLOBAL proj (i=1, last): write final x (f32) straight to d_out. grid 4096.
__global__ __launch_bounds__(256) void split_global_final(const short* __restrict__ Pout,
                                                          float* __restrict__ out) {
  int f = blockIdx.x;  // x flat row 0..4095
  int t = threadIdx.x;
  int pr = (f >> 11) * 2064 + 16 + (f & 2047);
  s16x4 v = *(const s16x4*)(Pout + (size_t)pr * 1024 + t * 4);
  f32x4 o;
#pragma unroll
  for (int j = 0; j < 4; ++j) o[j] = b2f(v[j]);
  *(f32x4*)(&out[(size_t)f * 1024 + t * 4]) = o;
}

// ---------------- orchestration ----------------
extern "C" void kernel_launch(void* const* d_in, const int* in_sizes, int n_in,
                              void* d_out, int out_size, void* d_ws, size_t ws_size,
                              hipStream_t stream) {
  const float* x_in = (const float*)d_in[0];
  const float* mem_in = (const float*)d_in[1];
  const float* lm_in = (const float*)d_in[2];
  const float* Wqkv_loc = (const float*)d_in[3];
  const float* Wproj_loc = (const float*)d_in[4];
  const float* g_loc = (const float*)d_in[5];
  const float* Wqkv_glob = (const float*)d_in[6];
  const float* Wproj_glob = (const float*)d_in[7];
  const float* g_glob = (const float*)d_in[8];

  char* ws = (char*)d_ws;
  size_t off = 0;
  auto alloc = [&](size_t bytes) {
    char* p = ws + off;
    off += (bytes + 255) & ~(size_t)255;
    return p;
  };
  short* Wt = (short*)alloc((size_t)3072 * 1024 * 2);
  float* lm_cur = (float*)alloc((size_t)256 * 1024 * 4);
  float* mem_cur = (float*)alloc((size_t)32 * 1024 * 4);
  short* Xin = (short*)alloc((size_t)MPAD * 1024 * 2);
  short* QKVb = (short*)alloc((size_t)MPAD * 3072 * 2);
  short* Yb = (short*)alloc((size_t)MPAD * 1024 * 2);
  short* Pout = (short*)alloc((size_t)MPAD * 1024 * 2);
  short* Vtb = (short*)alloc((size_t)256 * 64 * 320 * 2);
  size_t oacc_bytes = (size_t)32 * LG * 64 * 4;
  size_t lacc_bytes = (size_t)32 * LG * 4;
  float* o_acc = (float*)alloc(oacc_bytes);
  float* ls_acc = (float*)alloc(lacc_bytes);
  const bool use_split = (ws_size >= off);

  for (int i = 0; i < 2; ++i) {
    // ---- local attention (16 seqs, L=272, rows = 4352 = MPAD) ----
    transpose_cast<<<dim3(96, 32), dim3(32, 8), 0, stream>>>(
        Wqkv_loc + (size_t)i * 1024 * 3072, Wt, 1024, 3072);
    if (i == 0) build_xl<<<4352, 256, 0, stream>>>(x_in, lm_in, Xin);
    gemm_bt3<<<dim3(24, 34), 256, 0, stream>>>(Xin, Wt, QKVb, 1024, 3072);
    rmsnorm_qk<<<dim3(4352, 2), 256, 0, stream>>>(QKVb, g_loc + (size_t)i * 1024);
    transpose_v<<<dim3(10, 2, 256), dim3(32, 8), 0, stream>>>(QKVb, Vtb, 272, 320);
    attn_causal3<<<dim3(5, 16, 16), 256, 0, stream>>>(QKVb, Vtb, Yb, 272, 320);
    transpose_cast<<<dim3(32, 32), dim3(32, 8), 0, stream>>>(
        Wproj_loc + (size_t)i * 1024 * 1024, Wt, 1024, 1024);
    gemm_bt3<<<dim3(8, 34), 256, 0, stream>>>(Yb, Wt, Pout, 1024, 1024);
    split_local_build_xg<<<4608, 256, 0, stream>>>(Pout, i == 0 ? mem_in : mem_cur,
                                                   lm_cur, Xin);

    // ---- global attention (2 seqs, L=2064, rows = 4128; pads deterministic) ----
    transpose_cast<<<dim3(96, 32), dim3(32, 8), 0, stream>>>(
        Wqkv_glob + (size_t)i * 1024 * 3072, Wt, 1024, 3072);
    gemm_bt3<<<dim3(24, 34), 256, 0, stream>>>(Xin, Wt, QKVb, 1024, 3072);
    rmsnorm_qk<<<dim3(4128, 2), 256, 0, stream>>>(QKVb, g_glob + (size_t)i * 1024);
    transpose_v<<<dim3(66, 2, 32), dim3(32, 8), 0, stream>>>(QKVb, Vtb, 2064, 2112);
    if (use_split) {
      hipMemsetAsync(o_acc, 0, oacc_bytes, stream);
      hipMemsetAsync(ls_acc, 0, lacc_bytes, stream);
      attn_split<<<dim3(33, 5, 32), 256, 0, stream>>>(QKVb, Vtb, o_acc, ls_acc);
      attn_merge<<<dim3(516, 16, 2), 256, 0, stream>>>(o_acc, ls_acc, Yb);
    } else {
      attn_causal3<<<dim3(33, 16, 2), 256, 0, stream>>>(QKVb, Vtb, Yb, 2064, 2112);
    }
    transpose_cast<<<dim3(32, 32), dim3(32, 8), 0, stream>>>(
        Wproj_glob + (size_t)i * 1024 * 1024, Wt, 1024, 1024);
    gemm_bt3<<<dim3(8, 34), 256, 0, stream>>>(Yb, Wt, Pout, 1024, 1024);
    if (i == 0)
      split_global_build_xl<<<4384, 256, 0, stream>>>(Pout, lm_cur, mem_cur, Xin);
    else
      split_global_final<<<4096, 256, 0, stream>>>(Pout, (float*)d_out);
  }
}

// Round 9
// 603.179 us; speedup vs baseline: 1.0872x; 1.0044x over previous
//
#include <hip/hip_runtime.h>
#include <hip/hip_bf16.h>
#include <math.h>

typedef __attribute__((ext_vector_type(8))) short s16x8;
typedef __attribute__((ext_vector_type(4))) short s16x4;
typedef __attribute__((ext_vector_type(4))) float f32x4;

#define MPAD 4352   // = 34*128
#define LG 2064     // global seq length
#define CT 8        // k-tiles (of 64 keys) per split chunk
#define SM_SHIFT 11.5415603f  // 8 * log2(e); softmax = exp2(S*log2e - SM_SHIFT)

__device__ __forceinline__ short f2b(float f) {  // RNE (weights/activations)
  unsigned u = __float_as_uint(f);
  unsigned r = (u + 0x7fffu + ((u >> 16) & 1u)) >> 16;
  return (short)(unsigned short)r;
}
// round-half-up, 2 VALU ops: for softmax P writes (values in [0,1], symmetric ±2^-9 error)
__device__ __forceinline__ short f2b_fast(float f) {
  return (short)((__float_as_uint(f) + 0x8000u) >> 16);
}
__device__ __forceinline__ float b2f(short s) {
  return __uint_as_float(((unsigned)(unsigned short)s) << 16);
}

// global->LDS direct async copy, 16B per lane. LDS dest must be uniform-base + lane*16.
__device__ __forceinline__ void gl_lds16(const short* g, short* l) {
  __builtin_amdgcn_global_load_lds((const __attribute__((address_space(1))) short*)g,
                                   (__attribute__((address_space(3))) short*)l, 16, 0, 0);
}

// ---------------- transpose + cast: in f32 (K x N) -> out bf16 (N x K) ----------------
__global__ __launch_bounds__(256) void transpose_cast(const float* __restrict__ in,
                                                      short* __restrict__ out,
                                                      int K, int N) {
  __shared__ float tile[32][33];
  int bn = blockIdx.x * 32;
  int bk = blockIdx.y * 32;
  for (int i = threadIdx.y; i < 32; i += 8)
    tile[i][threadIdx.x] = in[(size_t)(bk + i) * N + bn + threadIdx.x];
  __syncthreads();
  for (int i = threadIdx.y; i < 32; i += 8)
    out[(size_t)(bn + i) * K + bk + threadIdx.x] = f2b(tile[threadIdx.x][i]);
}

// ---------------- V transpose: QKV V-slice -> Vt[s*16+h][64][Lpad]; covers FULL Lpad ----------------
__global__ __launch_bounds__(256) void transpose_v(const short* __restrict__ QKV,
                                                   short* __restrict__ Vt,
                                                   int L, int Lpad) {
  __shared__ short tile[32][33];
  int sh = blockIdx.z;
  int s = sh >> 4, h = sh & 15;
  int kb = blockIdx.x * 32;
  int cb = blockIdx.y * 32;
  int tx = threadIdx.x;
  for (int i = threadIdx.y; i < 32; i += 8) {
    int key = kb + i;
    if (key > L - 1) key = L - 1;
    tile[i][tx] = QKV[(size_t)(s * L + key) * 3072 + 2048 + h * 64 + cb + tx];
  }
  __syncthreads();
  for (int i = threadIdx.y; i < 32; i += 8)
    Vt[((size_t)sh * 64 + cb + i) * Lpad + kb + tx] = tile[tx][i];
}

// ---------------- GEMM v3: 2-phase prefetch, gl_lds dbuf, 1 barrier/iter ----------------
__global__ __launch_bounds__(256) void gemm_bt3(const short* __restrict__ A,
                                                const short* __restrict__ BT,
                                                short* __restrict__ C,
                                                int K, int N) {
  __shared__ short As[2][128 * 32];
  __shared__ short Bs[2][128 * 32];
  const int tid = threadIdx.x;
  const int lane = tid & 63;
  const int w = tid >> 6;
  const int wr = (w >> 1) * 64, wc = (w & 1) * 64;
  const int m0 = blockIdx.y * 128;
  const int n0 = blockIdx.x * 128;
  const int l15 = lane & 15, lhi = lane >> 4;

  f32x4 acc[4][4] = {};

  auto STAGE = [&](int b, int k0) {
#pragma unroll
    for (int p = 0; p < 2; ++p) {
      int g = w * 128 + p * 64 + lane;
      int row = g >> 2;
      int cs = (g & 3) * 8;
      gl_lds16(A + (size_t)(m0 + row) * K + k0 + cs, &As[b][g * 8]);
      gl_lds16(BT + (size_t)(n0 + row) * K + k0 + cs, &Bs[b][g * 8]);
    }
  };

  const int nt = K >> 5;
  STAGE(0, 0);
  __syncthreads();
  int cur = 0;
  for (int t = 0; t < nt; ++t) {
    if (t + 1 < nt) STAGE(cur ^ 1, (t + 1) << 5);
    s16x8 af[4], bf[4];
#pragma unroll
    for (int m = 0; m < 4; ++m)
      af[m] = *(const s16x8*)(&As[cur][(wr + m * 16 + l15) * 32 + lhi * 8]);
#pragma unroll
    for (int n = 0; n < 4; ++n)
      bf[n] = *(const s16x8*)(&Bs[cur][(wc + n * 16 + l15) * 32 + lhi * 8]);
#pragma unroll
    for (int m = 0; m < 4; ++m)
#pragma unroll
      for (int n = 0; n < 4; ++n)
        acc[m][n] = __builtin_amdgcn_mfma_f32_16x16x32_bf16(af[m], bf[n], acc[m][n], 0, 0, 0);
    __syncthreads();
    cur ^= 1;
  }
#pragma unroll
  for (int m = 0; m < 4; ++m) {
    int row_base = m0 + wr + m * 16 + lhi * 4;
#pragma unroll
    for (int n = 0; n < 4; ++n) {
      int col = n0 + wc + n * 16 + l15;
#pragma unroll
      for (int r = 0; r < 4; ++r)
        C[(size_t)(row_base + r) * N + col] = f2b(acc[m][n][r]);
    }
  }
}

// ---------------- RMSNorm on Q (with 1/8*log2e scale) and K slices of QKV, in place ----------------
__global__ __launch_bounds__(256) void rmsnorm_qk(short* __restrict__ QKV,
                                                  const float* __restrict__ g) {
  int row = blockIdx.x;
  int which = blockIdx.y;  // 0 = q, 1 = k
  size_t base = (size_t)row * 3072 + (size_t)which * 1024;
  int t = threadIdx.x;
  s16x4 in = *(const s16x4*)(QKV + base + t * 4);
  float v[4];
  float ss = 0.f;
#pragma unroll
  for (int j = 0; j < 4; ++j) {
    v[j] = b2f(in[j]);
    ss += v[j] * v[j];
  }
#pragma unroll
  for (int m = 32; m >= 1; m >>= 1) ss += __shfl_xor(ss, m);
  __shared__ float red[4];
  if ((t & 63) == 0) red[t >> 6] = ss;
  __syncthreads();
  float tot = red[0] + red[1] + red[2] + red[3];
  float inv = rsqrtf(tot * (1.0f / 1024.0f) + 1e-6f);
  if (which == 0) inv *= 0.125f * 1.44269504f;  // fold 1/sqrt(hd) AND log2(e) into Q
  s16x4 out;
#pragma unroll
  for (int j = 0; j < 4; ++j) out[j] = f2b(v[j] * inv * g[t * 4 + j]);
  *(s16x4*)(&QKV[base + t * 4]) = out;
}

// ---------------- causal flash attention (local + global fallback) ----------------
// MFMA C-init = -SM_SHIFT so p = exp2(st) directly (saves 16 v_sub/iter);
// Ps written via 2-op round-half-up (saves ~48 VALU insts/iter vs RNE).
__global__ __launch_bounds__(256) void attn_causal3(const short* __restrict__ QKV,
                                                    const short* __restrict__ Vt,
                                                    short* __restrict__ Y,
                                                    int L, int Lpad) {
  const int h = blockIdx.y, s = blockIdx.z;
  const int q0 = blockIdx.x * 64;
  const int tid = threadIdx.x;
  const int lane = tid & 63, w = tid >> 6;
  const int l15 = lane & 15, lhi = lane >> 4;
  const int row0 = s * L;

  __shared__ short Ks[64][72];
  __shared__ short Vs[2][64][72];
  __shared__ short Ps[4][16][72];

  int qld = q0 + w * 16 + l15;
  if (qld > L - 1) qld = L - 1;
  const size_t qrow = (size_t)(row0 + qld) * 3072 + h * 64;
  s16x8 qf0 = *(const s16x8*)(QKV + qrow + lhi * 8);
  s16x8 qf1 = *(const s16x8*)(QKV + qrow + 32 + lhi * 8);

  float lsum[4] = {0.f, 0.f, 0.f, 0.f};
  f32x4 o[4];
#pragma unroll
  for (int d = 0; d < 4; ++d) o[d] = f32x4{0.f, 0.f, 0.f, 0.f};

  const short* Vbase = Vt + (size_t)(s * 16 + h) * 64 * Lpad;

  s16x8 kreg[2], vreg[2];
#pragma unroll
  for (int p = 0; p < 2; ++p) {
    int g = tid + p * 256;
    int kr = g >> 3, cs = (g & 7) * 8;
    int krow = kr;
    if (krow > L - 1) krow = L - 1;
    kreg[p] = *(const s16x8*)(QKV + (size_t)(row0 + krow) * 3072 + 1024 + h * 64 + cs);
    vreg[p] = *(const s16x8*)(Vbase + (size_t)kr * Lpad + cs);
  }

  int buf = 0;
  for (int kb = 0; kb <= q0; kb += 64, buf ^= 1) {
#pragma unroll
    for (int p = 0; p < 2; ++p) {
      int g = tid + p * 256;
      int kr = g >> 3, cs = (g & 7) * 8;
      *(s16x8*)(&Ks[kr][cs]) = kreg[p];
      *(s16x8*)(&Vs[buf][kr][cs]) = vreg[p];
    }
    if (kb + 64 <= q0) {
#pragma unroll
      for (int p = 0; p < 2; ++p) {
        int g = tid + p * 256;
        int kr = g >> 3, cs = (g & 7) * 8;
        int krow = kb + 64 + kr;
        if (krow > L - 1) krow = L - 1;
        kreg[p] = *(const s16x8*)(QKV + (size_t)(row0 + krow) * 3072 + 1024 + h * 64 + cs);
        vreg[p] = *(const s16x8*)(Vbase + (size_t)kr * Lpad + kb + 64 + cs);
      }
    }
    __syncthreads();

    f32x4 st[4];
#pragma unroll
    for (int n = 0; n < 4; ++n) {
      s16x8 k0 = *(const s16x8*)(&Ks[n * 16 + l15][lhi * 8]);
      s16x8 k1 = *(const s16x8*)(&Ks[n * 16 + l15][32 + lhi * 8]);
      f32x4 sa = f32x4{-SM_SHIFT, -SM_SHIFT, -SM_SHIFT, -SM_SHIFT};
      sa = __builtin_amdgcn_mfma_f32_16x16x32_bf16(qf0, k0, sa, 0, 0, 0);
      sa = __builtin_amdgcn_mfma_f32_16x16x32_bf16(qf1, k1, sa, 0, 0, 0);
      st[n] = sa;
    }

    if (kb == q0) {
#pragma unroll
      for (int n = 0; n < 4; ++n) {
        int key = kb + n * 16 + l15;
#pragma unroll
        for (int r = 0; r < 4; ++r) {
          int qr = q0 + w * 16 + lhi * 4 + r;
          if (key > qr) st[n][r] = -1e30f;
        }
      }
    }

#pragma unroll
    for (int n = 0; n < 4; ++n) {
#pragma unroll
      for (int r = 0; r < 4; ++r) {
        float p = exp2f(st[n][r]);
        Ps[w][lhi * 4 + r][n * 16 + l15] = f2b_fast(p);
        lsum[r] += p;
      }
    }
    __syncthreads();

#pragma unroll
    for (int kk = 0; kk < 2; ++kk) {
      s16x8 pa = *(const s16x8*)(&Ps[w][l15][kk * 32 + lhi * 8]);
#pragma unroll
      for (int d = 0; d < 4; ++d) {
        s16x8 vf = *(const s16x8*)(&Vs[buf][d * 16 + l15][kk * 32 + lhi * 8]);
        o[d] = __builtin_amdgcn_mfma_f32_16x16x32_bf16(pa, vf, o[d], 0, 0, 0);
      }
    }
  }

#pragma unroll
  for (int r = 0; r < 4; ++r) {
#pragma unroll
    for (int mm = 1; mm <= 8; mm <<= 1) lsum[r] += __shfl_xor(lsum[r], mm, 16);
  }
#pragma unroll
  for (int d = 0; d < 4; ++d) {
#pragma unroll
    for (int r = 0; r < 4; ++r) {
      int qr = q0 + w * 16 + lhi * 4 + r;
      if (qr < L)
        Y[(size_t)(row0 + qr) * 1024 + h * 64 + d * 16 + l15] = f2b(o[d][r] / lsum[r]);
    }
  }
}

// ---------------- split-K causal attention (global, L=2064) ----------------
__global__ __launch_bounds__(256) void attn_split(const short* __restrict__ QKV,
                                                  const short* __restrict__ Vt,
                                                  float* __restrict__ o_acc,
                                                  float* __restrict__ ls_acc) {
  const int qb = blockIdx.x;
  const int chunk = blockIdx.y;
  const int sh = blockIdx.z;
  const int t0 = chunk * CT;
  if (t0 > qb) return;
  const int t1 = min(t0 + CT, qb + 1);
  const int h = sh & 15, s = sh >> 4;
  const int q0 = qb * 64;
  const int tid = threadIdx.x;
  const int lane = tid & 63, w = tid >> 6;
  const int l15 = lane & 15, lhi = lane >> 4;
  const int row0 = s * LG;
  const int Lpad = 2112;

  __shared__ short Ks[64][72];
  __shared__ short Vs[2][64][72];
  __shared__ short Ps[4][16][72];

  int qld = q0 + w * 16 + l15;
  if (qld > LG - 1) qld = LG - 1;
  const size_t qrow = (size_t)(row0 + qld) * 3072 + h * 64;
  s16x8 qf0 = *(const s16x8*)(QKV + qrow + lhi * 8);
  s16x8 qf1 = *(const s16x8*)(QKV + qrow + 32 + lhi * 8);

  float lsum[4] = {0.f, 0.f, 0.f, 0.f};
  f32x4 o[4];
#pragma unroll
  for (int d = 0; d < 4; ++d) o[d] = f32x4{0.f, 0.f, 0.f, 0.f};

  const short* Vbase = Vt + (size_t)sh * 64 * Lpad;

  s16x8 kreg[2], vreg[2];
  const int kb0 = t0 * 64;
#pragma unroll
  for (int p = 0; p < 2; ++p) {
    int g = tid + p * 256;
    int kr = g >> 3, cs = (g & 7) * 8;
    int krow = kb0 + kr;
    if (krow > LG - 1) krow = LG - 1;
    kreg[p] = *(const s16x8*)(QKV + (size_t)(row0 + krow) * 3072 + 1024 + h * 64 + cs);
    vreg[p] = *(const s16x8*)(Vbase + (size_t)kr * Lpad + kb0 + cs);
  }

  int buf = 0;
  for (int t = t0; t < t1; ++t, buf ^= 1) {
    const int kb = t * 64;
#pragma unroll
    for (int p = 0; p < 2; ++p) {
      int g = tid + p * 256;
      int kr = g >> 3, cs = (g & 7) * 8;
      *(s16x8*)(&Ks[kr][cs]) = kreg[p];
      *(s16x8*)(&Vs[buf][kr][cs]) = vreg[p];
    }
    if (t + 1 < t1) {
#pragma unroll
      for (int p = 0; p < 2; ++p) {
        int g = tid + p * 256;
        int kr = g >> 3, cs = (g & 7) * 8;
        int krow = kb + 64 + kr;
        if (krow > LG - 1) krow = LG - 1;
        kreg[p] = *(const s16x8*)(QKV + (size_t)(row0 + krow) * 3072 + 1024 + h * 64 + cs);
        vreg[p] = *(const s16x8*)(Vbase + (size_t)kr * Lpad + kb + 64 + cs);
      }
    }
    __syncthreads();

    f32x4 st[4];
#pragma unroll
    for (int n = 0; n < 4; ++n) {
      s16x8 k0 = *(const s16x8*)(&Ks[n * 16 + l15][lhi * 8]);
      s16x8 k1 = *(const s16x8*)(&Ks[n * 16 + l15][32 + lhi * 8]);
      f32x4 sa = f32x4{-SM_SHIFT, -SM_SHIFT, -SM_SHIFT, -SM_SHIFT};
      sa = __builtin_amdgcn_mfma_f32_16x16x32_bf16(qf0, k0, sa, 0, 0, 0);
      sa = __builtin_amdgcn_mfma_f32_16x16x32_bf16(qf1, k1, sa, 0, 0, 0);
      st[n] = sa;
    }

    if (t == qb) {
#pragma unroll
      for (int n = 0; n < 4; ++n) {
        int key = kb + n * 16 + l15;
#pragma unroll
        for (int r = 0; r < 4; ++r) {
          int qr = q0 + w * 16 + lhi * 4 + r;
          if (key > qr) st[n][r] = -1e30f;
        }
      }
    }

#pragma unroll
    for (int n = 0; n < 4; ++n) {
#pragma unroll
      for (int r = 0; r < 4; ++r) {
        float p = exp2f(st[n][r]);
        Ps[w][lhi * 4 + r][n * 16 + l15] = f2b_fast(p);
        lsum[r] += p;
      }
    }
    __syncthreads();

#pragma unroll
    for (int kk = 0; kk < 2; ++kk) {
      s16x8 pa = *(const s16x8*)(&Ps[w][l15][kk * 32 + lhi * 8]);
#pragma unroll
      for (int d = 0; d < 4; ++d) {
        s16x8 vf = *(const s16x8*)(&Vs[buf][d * 16 + l15][kk * 32 + lhi * 8]);
        o[d] = __builtin_amdgcn_mfma_f32_16x16x32_bf16(pa, vf, o[d], 0, 0, 0);
      }
    }
  }

#pragma unroll
  for (int r = 0; r < 4; ++r) {
#pragma unroll
    for (int mm = 1; mm <= 8; mm <<= 1) lsum[r] += __shfl_xor(lsum[r], mm, 16);
  }
#pragma unroll
  for (int r = 0; r < 4; ++r) {
    int qr = q0 + w * 16 + lhi * 4 + r;
    if (qr < LG) {
      if (l15 == 0) atomicAdd(&ls_acc[(size_t)sh * LG + qr], lsum[r]);
#pragma unroll
      for (int d = 0; d < 4; ++d)
        atomicAdd(&o_acc[((size_t)sh * LG + qr) * 64 + d * 16 + l15], o[d][r]);
    }
  }
}

// merge: Y = o_acc / ls_acc
__global__ __launch_bounds__(256) void attn_merge(const float* __restrict__ o_acc,
                                                  const float* __restrict__ ls_acc,
                                                  short* __restrict__ Y) {
  int sh = blockIdx.z * 16 + blockIdx.y;
  int s = sh >> 4, h = sh & 15;
  int row = blockIdx.x * 4 + (threadIdx.x >> 6);
  int col = threadIdx.x & 63;
  if (row < LG) {
    float inv = 1.0f / ls_acc[(size_t)sh * LG + row];
    float v = o_acc[((size_t)sh * LG + row) * 64 + col];
    Y[(size_t)(s * LG + row) * 1024 + h * 64 + col] = f2b(v * inv);
  }
}

// ---------------- fused gather/scatter ----------------
__global__ __launch_bounds__(256) void build_xl(const float* __restrict__ x,
                                                const float* __restrict__ lm,
                                                short* __restrict__ Xin) {
  int row = blockIdx.x;  // 0..4351
  int s = row / 272, r = row % 272;
  const float* src = (r < 16) ? lm + ((size_t)s * 16 + r) * 1024
                              : x + ((size_t)s * 256 + (r - 16)) * 1024;
  int t = threadIdx.x;
  f32x4 v = *(const f32x4*)(src + t * 4);
  s16x4 o;
#pragma unroll
  for (int j = 0; j < 4; ++j) o[j] = f2b(v[j]);
  *(s16x4*)(&Xin[(size_t)row * 1024 + t * 4]) = o;
}

__global__ __launch_bounds__(256) void split_local_build_xg(const short* __restrict__ Pout,
                                                            const float* __restrict__ mem_src,
                                                            float* __restrict__ lm_out,
                                                            short* __restrict__ Xin) {
  int row = blockIdx.x;
  int t = threadIdx.x;
  if (row < 4352) {
    int sr = row < 4128 ? row : 4127;
    int b = sr / 2064, r = sr % 2064;
    s16x4 o;
    if (r < 16) {
      f32x4 v = *(const f32x4*)(mem_src + ((size_t)(b * 16 + r)) * 1024 + t * 4);
#pragma unroll
      for (int j = 0; j < 4; ++j) o[j] = f2b(v[j]);
    } else {
      int f = b * 2048 + (r - 16);
      int pr = (f >> 8) * 272 + 16 + (f & 255);
      o = *(const s16x4*)(Pout + (size_t)pr * 1024 + t * 4);
    }
    *(s16x4*)(&Xin[(size_t)row * 1024 + t * 4]) = o;
  } else {
    int m = row - 4352;
    int pr = (m >> 4) * 272 + (m & 15);
    s16x4 v = *(const s16x4*)(Pout + (size_t)pr * 1024 + t * 4);
    f32x4 o;
#pragma unroll
    for (int j = 0; j < 4; ++j) o[j] = b2f(v[j]);
    *(f32x4*)(&lm_out[(size_t)m * 1024 + t * 4]) = o;
  }
}

__global__ __launch_bounds__(256) void split_global_build_xl(const short* __restrict__ Pout,
                                                             const float* __restrict__ lm_src,
                                                             float* __restrict__ mem_out,
                                                             short* __restrict__ Xin) {
  int row = blockIdx.x;
  int t = threadIdx.x;
  if (row < 4352) {
    int s = row / 272, r = row % 272;
    s16x4 o;
    if (r < 16) {
      f32x4 v = *(const f32x4*)(lm_src + ((size_t)(s * 16 + r)) * 1024 + t * 4);
#pragma unroll
      for (int j = 0; j < 4; ++j) o[j] = f2b(v[j]);
    } else {
      int f = s * 256 + (r - 16);
      int pr = (f >> 11) * 2064 + 16 + (f & 2047);
      o = *(const s16x4*)(Pout + (size_t)pr * 1024 + t * 4);
    }
    *(s16x4*)(&Xin[(size_t)row * 1024 + t * 4]) = o;
  } else {
    int m = row - 4352;
    int pr = (m >> 4) * 2064 + (m & 15);
    s16x4 v = *(const s16x4*)(Pout + (size_t)pr * 1024 + t * 4);
    f32x4 o;
#pragma unroll
    for (int j = 0; j < 4; ++j) o[j] = b2f(v[j]);
    *(f32x4*)(&mem_out[(size_t)m * 1024 + t * 4]) = o;
  }
}

__global__ __launch_bounds__(256) void split_global_final(const short* __restrict__ Pout,
                                                          float* __restrict__ out) {
  int f = blockIdx.x;
  int t = threadIdx.x;
  int pr = (f >> 11) * 2064 + 16 + (f & 2047);
  s16x4 v = *(const s16x4*)(Pout + (size_t)pr * 1024 + t * 4);
  f32x4 o;
#pragma unroll
  for (int j = 0; j < 4; ++j) o[j] = b2f(v[j]);
  *(f32x4*)(&out[(size_t)f * 1024 + t * 4]) = o;
}

// ---------------- orchestration ----------------
extern "C" void kernel_launch(void* const* d_in, const int* in_sizes, int n_in,
                              void* d_out, int out_size, void* d_ws, size_t ws_size,
                              hipStream_t stream) {
  const float* x_in = (const float*)d_in[0];
  const float* mem_in = (const float*)d_in[1];
  const float* lm_in = (const float*)d_in[2];
  const float* Wqkv_loc = (const float*)d_in[3];
  const float* Wproj_loc = (const float*)d_in[4];
  const float* g_loc = (const float*)d_in[5];
  const float* Wqkv_glob = (const float*)d_in[6];
  const float* Wproj_glob = (const float*)d_in[7];
  const float* g_glob = (const float*)d_in[8];

  char* ws = (char*)d_ws;
  size_t off = 0;
  auto alloc = [&](size_t bytes) {
    char* p = ws + off;
    off += (bytes + 255) & ~(size_t)255;
    return p;
  };
  short* Wt = (short*)alloc((size_t)3072 * 1024 * 2);
  float* lm_cur = (float*)alloc((size_t)256 * 1024 * 4);
  float* mem_cur = (float*)alloc((size_t)32 * 1024 * 4);
  short* Xin = (short*)alloc((size_t)MPAD * 1024 * 2);
  short* QKVb = (short*)alloc((size_t)MPAD * 3072 * 2);
  short* Yb = (short*)alloc((size_t)MPAD * 1024 * 2);
  short* Pout = (short*)alloc((size_t)MPAD * 1024 * 2);
  short* Vtb = (short*)alloc((size_t)256 * 64 * 320 * 2);
  size_t oacc_bytes = (size_t)32 * LG * 64 * 4;
  size_t lacc_bytes = (size_t)32 * LG * 4;
  float* o_acc = (float*)alloc(oacc_bytes);
  float* ls_acc = (float*)alloc(lacc_bytes);
  const bool use_split = (ws_size >= off);

  for (int i = 0; i < 2; ++i) {
    // ---- local attention (16 seqs, L=272, rows = 4352 = MPAD) ----
    transpose_cast<<<dim3(96, 32), dim3(32, 8), 0, stream>>>(
        Wqkv_loc + (size_t)i * 1024 * 3072, Wt, 1024, 3072);
    if (i == 0) build_xl<<<4352, 256, 0, stream>>>(x_in, lm_in, Xin);
    gemm_bt3<<<dim3(24, 34), 256, 0, stream>>>(Xin, Wt, QKVb, 1024, 3072);
    rmsnorm_qk<<<dim3(4352, 2), 256, 0, stream>>>(QKVb, g_loc + (size_t)i * 1024);
    transpose_v<<<dim3(10, 2, 256), dim3(32, 8), 0, stream>>>(QKVb, Vtb, 272, 320);
    attn_causal3<<<dim3(5, 16, 16), 256, 0, stream>>>(QKVb, Vtb, Yb, 272, 320);
    transpose_cast<<<dim3(32, 32), dim3(32, 8), 0, stream>>>(
        Wproj_loc + (size_t)i * 1024 * 1024, Wt, 1024, 1024);
    gemm_bt3<<<dim3(8, 34), 256, 0, stream>>>(Yb, Wt, Pout, 1024, 1024);
    split_local_build_xg<<<4608, 256, 0, stream>>>(Pout, i == 0 ? mem_in : mem_cur,
                                                   lm_cur, Xin);

    // ---- global attention (2 seqs, L=2064, rows = 4128; pads deterministic) ----
    transpose_cast<<<dim3(96, 32), dim3(32, 8), 0, stream>>>(
        Wqkv_glob + (size_t)i * 1024 * 3072, Wt, 1024, 3072);
    gemm_bt3<<<dim3(24, 34), 256, 0, stream>>>(Xin, Wt, QKVb, 1024, 3072);
    rmsnorm_qk<<<dim3(4128, 2), 256, 0, stream>>>(QKVb, g_glob + (size_t)i * 1024);
    transpose_v<<<dim3(66, 2, 32), dim3(32, 8), 0, stream>>>(QKVb, Vtb, 2064, 2112);
    if (use_split) {
      hipMemsetAsync(o_acc, 0, oacc_bytes, stream);
      hipMemsetAsync(ls_acc, 0, lacc_bytes, stream);
      attn_split<<<dim3(33, 5, 32), 256, 0, stream>>>(QKVb, Vtb, o_acc, ls_acc);
      attn_merge<<<dim3(516, 16, 2), 256, 0, stream>>>(o_acc, ls_acc, Yb);
    } else {
      attn_causal3<<<dim3(33, 16, 2), 256, 0, stream>>>(QKVb, Vtb, Yb, 2064, 2112);
    }
    transpose_cast<<<dim3(32, 32), dim3(32, 8), 0, stream>>>(
        Wproj_glob + (size_t)i * 1024 * 1024, Wt, 1024, 1024);
    gemm_bt3<<<dim3(8, 34), 256, 0, stream>>>(Yb, Wt, Pout, 1024, 1024);
    if (i == 0)
      split_global_build_xl<<<4384, 256, 0, stream>>>(Pout, lm_cur, mem_cur, Xin);
    else
      split_global_final<<<4096, 256, 0, stream>>>(Pout, (float*)d_out);
  }
}

// Round 10
// 593.437 us; speedup vs baseline: 1.1051x; 1.0164x over previous
//
#include <hip/hip_runtime.h>
#include <hip/hip_bf16.h>
#include <math.h>

typedef __attribute__((ext_vector_type(8))) short s16x8;
typedef __attribute__((ext_vector_type(4))) short s16x4;
typedef __attribute__((ext_vector_type(4))) float f32x4;

#define MPAD 4352   // = 34*128
#define LG 2064     // global seq length
#define CT 8        // k-tiles (of 64 keys) per split chunk
#define SM_SHIFT 11.5415603f  // 8 * log2(e); softmax = exp2(S*log2e - SM_SHIFT)
#define PS_LD 80    // Ps row stride in shorts: 160B => conflict-free b16 writes

__device__ __forceinline__ short f2b(float f) {  // RNE (weights/activations)
  unsigned u = __float_as_uint(f);
  unsigned r = (u + 0x7fffu + ((u >> 16) & 1u)) >> 16;
  return (short)(unsigned short)r;
}
// round-half-up, 2 VALU ops: for softmax P writes (values in [0,1], symmetric ±2^-9 error)
__device__ __forceinline__ short f2b_fast(float f) {
  return (short)((__float_as_uint(f) + 0x8000u) >> 16);
}
__device__ __forceinline__ float b2f(short s) {
  return __uint_as_float(((unsigned)(unsigned short)s) << 16);
}
// raw v_exp_f32 (1 inst; libm exp2f carries a denormal-guard sequence)
__device__ __forceinline__ float fexp2(float x) {
#if __has_builtin(__builtin_amdgcn_exp2f)
  return __builtin_amdgcn_exp2f(x);
#else
  float r;
  asm("v_exp_f32 %0, %1" : "=v"(r) : "v"(x));
  return r;
#endif
}

// global->LDS direct async copy, 16B per lane. LDS dest must be uniform-base + lane*16.
__device__ __forceinline__ void gl_lds16(const short* g, short* l) {
  __builtin_amdgcn_global_load_lds((const __attribute__((address_space(1))) short*)g,
                                   (__attribute__((address_space(3))) short*)l, 16, 0, 0);
}

// ---------------- transpose + cast: in f32 (K x N) -> out bf16 (N x K) ----------------
__global__ __launch_bounds__(256) void transpose_cast(const float* __restrict__ in,
                                                      short* __restrict__ out,
                                                      int K, int N) {
  __shared__ float tile[32][33];
  int bn = blockIdx.x * 32;
  int bk = blockIdx.y * 32;
  for (int i = threadIdx.y; i < 32; i += 8)
    tile[i][threadIdx.x] = in[(size_t)(bk + i) * N + bn + threadIdx.x];
  __syncthreads();
  for (int i = threadIdx.y; i < 32; i += 8)
    out[(size_t)(bn + i) * K + bk + threadIdx.x] = f2b(tile[threadIdx.x][i]);
}

// ---------------- V transpose: QKV V-slice -> Vt[s*16+h][64][Lpad]; covers FULL Lpad ----------------
__global__ __launch_bounds__(256) void transpose_v(const short* __restrict__ QKV,
                                                   short* __restrict__ Vt,
                                                   int L, int Lpad) {
  __shared__ short tile[32][33];
  int sh = blockIdx.z;
  int s = sh >> 4, h = sh & 15;
  int kb = blockIdx.x * 32;
  int cb = blockIdx.y * 32;
  int tx = threadIdx.x;
  for (int i = threadIdx.y; i < 32; i += 8) {
    int key = kb + i;
    if (key > L - 1) key = L - 1;
    tile[i][tx] = QKV[(size_t)(s * L + key) * 3072 + 2048 + h * 64 + cb + tx];
  }
  __syncthreads();
  for (int i = threadIdx.y; i < 32; i += 8)
    Vt[((size_t)sh * 64 + cb + i) * Lpad + kb + tx] = tile[tx][i];
}

// ---------------- GEMM v3: 2-phase prefetch, gl_lds dbuf, 1 barrier/iter ----------------
__global__ __launch_bounds__(256) void gemm_bt3(const short* __restrict__ A,
                                                const short* __restrict__ BT,
                                                short* __restrict__ C,
                                                int K, int N) {
  __shared__ short As[2][128 * 32];
  __shared__ short Bs[2][128 * 32];
  const int tid = threadIdx.x;
  const int lane = tid & 63;
  const int w = tid >> 6;
  const int wr = (w >> 1) * 64, wc = (w & 1) * 64;
  const int m0 = blockIdx.y * 128;
  const int n0 = blockIdx.x * 128;
  const int l15 = lane & 15, lhi = lane >> 4;

  f32x4 acc[4][4] = {};

  auto STAGE = [&](int b, int k0) {
#pragma unroll
    for (int p = 0; p < 2; ++p) {
      int g = w * 128 + p * 64 + lane;
      int row = g >> 2;
      int cs = (g & 3) * 8;
      gl_lds16(A + (size_t)(m0 + row) * K + k0 + cs, &As[b][g * 8]);
      gl_lds16(BT + (size_t)(n0 + row) * K + k0 + cs, &Bs[b][g * 8]);
    }
  };

  const int nt = K >> 5;
  STAGE(0, 0);
  __syncthreads();
  int cur = 0;
  for (int t = 0; t < nt; ++t) {
    if (t + 1 < nt) STAGE(cur ^ 1, (t + 1) << 5);
    s16x8 af[4], bf[4];
#pragma unroll
    for (int m = 0; m < 4; ++m)
      af[m] = *(const s16x8*)(&As[cur][(wr + m * 16 + l15) * 32 + lhi * 8]);
#pragma unroll
    for (int n = 0; n < 4; ++n)
      bf[n] = *(const s16x8*)(&Bs[cur][(wc + n * 16 + l15) * 32 + lhi * 8]);
#pragma unroll
    for (int m = 0; m < 4; ++m)
#pragma unroll
      for (int n = 0; n < 4; ++n)
        acc[m][n] = __builtin_amdgcn_mfma_f32_16x16x32_bf16(af[m], bf[n], acc[m][n], 0, 0, 0);
    __syncthreads();
    cur ^= 1;
  }
#pragma unroll
  for (int m = 0; m < 4; ++m) {
    int row_base = m0 + wr + m * 16 + lhi * 4;
#pragma unroll
    for (int n = 0; n < 4; ++n) {
      int col = n0 + wc + n * 16 + l15;
#pragma unroll
      for (int r = 0; r < 4; ++r)
        C[(size_t)(row_base + r) * N + col] = f2b(acc[m][n][r]);
    }
  }
}

// ---------------- RMSNorm on Q (with 1/8*log2e scale) and K slices of QKV, in place ----------------
__global__ __launch_bounds__(256) void rmsnorm_qk(short* __restrict__ QKV,
                                                  const float* __restrict__ g) {
  int row = blockIdx.x;
  int which = blockIdx.y;  // 0 = q, 1 = k
  size_t base = (size_t)row * 3072 + (size_t)which * 1024;
  int t = threadIdx.x;
  s16x4 in = *(const s16x4*)(QKV + base + t * 4);
  float v[4];
  float ss = 0.f;
#pragma unroll
  for (int j = 0; j < 4; ++j) {
    v[j] = b2f(in[j]);
    ss += v[j] * v[j];
  }
#pragma unroll
  for (int m = 32; m >= 1; m >>= 1) ss += __shfl_xor(ss, m);
  __shared__ float red[4];
  if ((t & 63) == 0) red[t >> 6] = ss;
  __syncthreads();
  float tot = red[0] + red[1] + red[2] + red[3];
  float inv = rsqrtf(tot * (1.0f / 1024.0f) + 1e-6f);
  if (which == 0) inv *= 0.125f * 1.44269504f;  // fold 1/sqrt(hd) AND log2(e) into Q
  s16x4 out;
#pragma unroll
  for (int j = 0; j < 4; ++j) out[j] = f2b(v[j] * inv * g[t * 4 + j]);
  *(s16x4*)(&QKV[base + t * 4]) = out;
}

// ---------------- causal flash attention (local + global fallback) ----------------
// MFMA C-init = -SM_SHIFT so p = exp2(st) directly; raw v_exp_f32; Ps row stride 80
// (160B) so the 16 b16 P-writes/iter are bank-conflict-free.
__global__ __launch_bounds__(256) void attn_causal3(const short* __restrict__ QKV,
                                                    const short* __restrict__ Vt,
                                                    short* __restrict__ Y,
                                                    int L, int Lpad) {
  const int h = blockIdx.y, s = blockIdx.z;
  const int q0 = blockIdx.x * 64;
  const int tid = threadIdx.x;
  const int lane = tid & 63, w = tid >> 6;
  const int l15 = lane & 15, lhi = lane >> 4;
  const int row0 = s * L;

  __shared__ short Ks[64][72];
  __shared__ short Vs[2][64][72];
  __shared__ short Ps[4][16][PS_LD];

  int qld = q0 + w * 16 + l15;
  if (qld > L - 1) qld = L - 1;
  const size_t qrow = (size_t)(row0 + qld) * 3072 + h * 64;
  s16x8 qf0 = *(const s16x8*)(QKV + qrow + lhi * 8);
  s16x8 qf1 = *(const s16x8*)(QKV + qrow + 32 + lhi * 8);

  float lsum[4] = {0.f, 0.f, 0.f, 0.f};
  f32x4 o[4];
#pragma unroll
  for (int d = 0; d < 4; ++d) o[d] = f32x4{0.f, 0.f, 0.f, 0.f};

  const short* Vbase = Vt + (size_t)(s * 16 + h) * 64 * Lpad;

  s16x8 kreg[2], vreg[2];
#pragma unroll
  for (int p = 0; p < 2; ++p) {
    int g = tid + p * 256;
    int kr = g >> 3, cs = (g & 7) * 8;
    int krow = kr;
    if (krow > L - 1) krow = L - 1;
    kreg[p] = *(const s16x8*)(QKV + (size_t)(row0 + krow) * 3072 + 1024 + h * 64 + cs);
    vreg[p] = *(const s16x8*)(Vbase + (size_t)kr * Lpad + cs);
  }

  int buf = 0;
  for (int kb = 0; kb <= q0; kb += 64, buf ^= 1) {
#pragma unroll
    for (int p = 0; p < 2; ++p) {
      int g = tid + p * 256;
      int kr = g >> 3, cs = (g & 7) * 8;
      *(s16x8*)(&Ks[kr][cs]) = kreg[p];
      *(s16x8*)(&Vs[buf][kr][cs]) = vreg[p];
    }
    if (kb + 64 <= q0) {
#pragma unroll
      for (int p = 0; p < 2; ++p) {
        int g = tid + p * 256;
        int kr = g >> 3, cs = (g & 7) * 8;
        int krow = kb + 64 + kr;
        if (krow > L - 1) krow = L - 1;
        kreg[p] = *(const s16x8*)(QKV + (size_t)(row0 + krow) * 3072 + 1024 + h * 64 + cs);
        vreg[p] = *(const s16x8*)(Vbase + (size_t)kr * Lpad + kb + 64 + cs);
      }
    }
    __syncthreads();

    f32x4 st[4];
#pragma unroll
    for (int n = 0; n < 4; ++n) {
      s16x8 k0 = *(const s16x8*)(&Ks[n * 16 + l15][lhi * 8]);
      s16x8 k1 = *(const s16x8*)(&Ks[n * 16 + l15][32 + lhi * 8]);
      f32x4 sa = f32x4{-SM_SHIFT, -SM_SHIFT, -SM_SHIFT, -SM_SHIFT};
      sa = __builtin_amdgcn_mfma_f32_16x16x32_bf16(qf0, k0, sa, 0, 0, 0);
      sa = __builtin_amdgcn_mfma_f32_16x16x32_bf16(qf1, k1, sa, 0, 0, 0);
      st[n] = sa;
    }

    if (kb == q0) {
#pragma unroll
      for (int n = 0; n < 4; ++n) {
        int key = kb + n * 16 + l15;
#pragma unroll
        for (int r = 0; r < 4; ++r) {
          int qr = q0 + w * 16 + lhi * 4 + r;
          if (key > qr) st[n][r] = -1e30f;
        }
      }
    }

#pragma unroll
    for (int n = 0; n < 4; ++n) {
#pragma unroll
      for (int r = 0; r < 4; ++r) {
        float p = fexp2(st[n][r]);
        Ps[w][lhi * 4 + r][n * 16 + l15] = f2b_fast(p);
        lsum[r] += p;
      }
    }
    __syncthreads();

#pragma unroll
    for (int kk = 0; kk < 2; ++kk) {
      s16x8 pa = *(const s16x8*)(&Ps[w][l15][kk * 32 + lhi * 8]);
#pragma unroll
      for (int d = 0; d < 4; ++d) {
        s16x8 vf = *(const s16x8*)(&Vs[buf][d * 16 + l15][kk * 32 + lhi * 8]);
        o[d] = __builtin_amdgcn_mfma_f32_16x16x32_bf16(pa, vf, o[d], 0, 0, 0);
      }
    }
  }

#pragma unroll
  for (int r = 0; r < 4; ++r) {
#pragma unroll
    for (int mm = 1; mm <= 8; mm <<= 1) lsum[r] += __shfl_xor(lsum[r], mm, 16);
  }
#pragma unroll
  for (int d = 0; d < 4; ++d) {
#pragma unroll
    for (int r = 0; r < 4; ++r) {
      int qr = q0 + w * 16 + lhi * 4 + r;
      if (qr < L)
        Y[(size_t)(row0 + qr) * 1024 + h * 64 + d * 16 + l15] = f2b(o[d][r] / lsum[r]);
    }
  }
}

// ---------------- split-K causal attention (global, L=2064) ----------------
__global__ __launch_bounds__(256) void attn_split(const short* __restrict__ QKV,
                                                  const short* __restrict__ Vt,
                                                  float* __restrict__ o_acc,
                                                  float* __restrict__ ls_acc) {
  const int qb = blockIdx.x;
  const int chunk = blockIdx.y;
  const int sh = blockIdx.z;
  const int t0 = chunk * CT;
  if (t0 > qb) return;
  const int t1 = min(t0 + CT, qb + 1);
  const int h = sh & 15, s = sh >> 4;
  const int q0 = qb * 64;
  const int tid = threadIdx.x;
  const int lane = tid & 63, w = tid >> 6;
  const int l15 = lane & 15, lhi = lane >> 4;
  const int row0 = s * LG;
  const int Lpad = 2112;

  __shared__ short Ks[64][72];
  __shared__ short Vs[2][64][72];
  __shared__ short Ps[4][16][PS_LD];

  int qld = q0 + w * 16 + l15;
  if (qld > LG - 1) qld = LG - 1;
  const size_t qrow = (size_t)(row0 + qld) * 3072 + h * 64;
  s16x8 qf0 = *(const s16x8*)(QKV + qrow + lhi * 8);
  s16x8 qf1 = *(const s16x8*)(QKV + qrow + 32 + lhi * 8);

  float lsum[4] = {0.f, 0.f, 0.f, 0.f};
  f32x4 o[4];
#pragma unroll
  for (int d = 0; d < 4; ++d) o[d] = f32x4{0.f, 0.f, 0.f, 0.f};

  const short* Vbase = Vt + (size_t)sh * 64 * Lpad;

  s16x8 kreg[2], vreg[2];
  const int kb0 = t0 * 64;
#pragma unroll
  for (int p = 0; p < 2; ++p) {
    int g = tid + p * 256;
    int kr = g >> 3, cs = (g & 7) * 8;
    int krow = kb0 + kr;
    if (krow > LG - 1) krow = LG - 1;
    kreg[p] = *(const s16x8*)(QKV + (size_t)(row0 + krow) * 3072 + 1024 + h * 64 + cs);
    vreg[p] = *(const s16x8*)(Vbase + (size_t)kr * Lpad + kb0 + cs);
  }

  int buf = 0;
  for (int t = t0; t < t1; ++t, buf ^= 1) {
    const int kb = t * 64;
#pragma unroll
    for (int p = 0; p < 2; ++p) {
      int g = tid + p * 256;
      int kr = g >> 3, cs = (g & 7) * 8;
      *(s16x8*)(&Ks[kr][cs]) = kreg[p];
      *(s16x8*)(&Vs[buf][kr][cs]) = vreg[p];
    }
    if (t + 1 < t1) {
#pragma unroll
      for (int p = 0; p < 2; ++p) {
        int g = tid + p * 256;
        int kr = g >> 3, cs = (g & 7) * 8;
        int krow = kb + 64 + kr;
        if (krow > LG - 1) krow = LG - 1;
        kreg[p] = *(const s16x8*)(QKV + (size_t)(row0 + krow) * 3072 + 1024 + h * 64 + cs);
        vreg[p] = *(const s16x8*)(Vbase + (size_t)kr * Lpad + kb + 64 + cs);
      }
    }
    __syncthreads();

    f32x4 st[4];
#pragma unroll
    for (int n = 0; n < 4; ++n) {
      s16x8 k0 = *(const s16x8*)(&Ks[n * 16 + l15][lhi * 8]);
      s16x8 k1 = *(const s16x8*)(&Ks[n * 16 + l15][32 + lhi * 8]);
      f32x4 sa = f32x4{-SM_SHIFT, -SM_SHIFT, -SM_SHIFT, -SM_SHIFT};
      sa = __builtin_amdgcn_mfma_f32_16x16x32_bf16(qf0, k0, sa, 0, 0, 0);
      sa = __builtin_amdgcn_mfma_f32_16x16x32_bf16(qf1, k1, sa, 0, 0, 0);
      st[n] = sa;
    }

    if (t == qb) {
#pragma unroll
      for (int n = 0; n < 4; ++n) {
        int key = kb + n * 16 + l15;
#pragma unroll
        for (int r = 0; r < 4; ++r) {
          int qr = q0 + w * 16 + lhi * 4 + r;
          if (key > qr) st[n][r] = -1e30f;
        }
      }
    }

#pragma unroll
    for (int n = 0; n < 4; ++n) {
#pragma unroll
      for (int r = 0; r < 4; ++r) {
        float p = fexp2(st[n][r]);
        Ps[w][lhi * 4 + r][n * 16 + l15] = f2b_fast(p);
        lsum[r] += p;
      }
    }
    __syncthreads();

#pragma unroll
    for (int kk = 0; kk < 2; ++kk) {
      s16x8 pa = *(const s16x8*)(&Ps[w][l15][kk * 32 + lhi * 8]);
#pragma unroll
      for (int d = 0; d < 4; ++d) {
        s16x8 vf = *(const s16x8*)(&Vs[buf][d * 16 + l15][kk * 32 + lhi * 8]);
        o[d] = __builtin_amdgcn_mfma_f32_16x16x32_bf16(pa, vf, o[d], 0, 0, 0);
      }
    }
  }

#pragma unroll
  for (int r = 0; r < 4; ++r) {
#pragma unroll
    for (int mm = 1; mm <= 8; mm <<= 1) lsum[r] += __shfl_xor(lsum[r], mm, 16);
  }
#pragma unroll
  for (int r = 0; r < 4; ++r) {
    int qr = q0 + w * 16 + lhi * 4 + r;
    if (qr < LG) {
      if (l15 == 0) atomicAdd(&ls_acc[(size_t)sh * LG + qr], lsum[r]);
#pragma unroll
      for (int d = 0; d < 4; ++d)
        atomicAdd(&o_acc[((size_t)sh * LG + qr) * 64 + d * 16 + l15], o[d][r]);
    }
  }
}

// merge: Y = o_acc / ls_acc
__global__ __launch_bounds__(256) void attn_merge(const float* __restrict__ o_acc,
                                                  const float* __restrict__ ls_acc,
                                                  short* __restrict__ Y) {
  int sh = blockIdx.z * 16 + blockIdx.y;
  int s = sh >> 4, h = sh & 15;
  int row = blockIdx.x * 4 + (threadIdx.x >> 6);
  int col = threadIdx.x & 63;
  if (row < LG) {
    float inv = 1.0f / ls_acc[(size_t)sh * LG + row];
    float v = o_acc[((size_t)sh * LG + row) * 64 + col];
    Y[(size_t)(s * LG + row) * 1024 + h * 64 + col] = f2b(v * inv);
  }
}

// ---------------- fused gather/scatter ----------------
__global__ __launch_bounds__(256) void build_xl(const float* __restrict__ x,
                                                const float* __restrict__ lm,
                                                short* __restrict__ Xin) {
  int row = blockIdx.x;  // 0..4351
  int s = row / 272, r = row % 272;
  const float* src = (r < 16) ? lm + ((size_t)s * 16 + r) * 1024
                              : x + ((size_t)s * 256 + (r - 16)) * 1024;
  int t = threadIdx.x;
  f32x4 v = *(const f32x4*)(src + t * 4);
  s16x4 o;
#pragma unroll
  for (int j = 0; j < 4; ++j) o[j] = f2b(v[j]);
  *(s16x4*)(&Xin[(size_t)row * 1024 + t * 4]) = o;
}

__global__ __launch_bounds__(256) void split_local_build_xg(const short* __restrict__ Pout,
                                                            const float* __restrict__ mem_src,
                                                            float* __restrict__ lm_out,
                                                            short* __restrict__ Xin) {
  int row = blockIdx.x;
  int t = threadIdx.x;
  if (row < 4352) {
    int sr = row < 4128 ? row : 4127;
    int b = sr / 2064, r = sr % 2064;
    s16x4 o;
    if (r < 16) {
      f32x4 v = *(const f32x4*)(mem_src + ((size_t)(b * 16 + r)) * 1024 + t * 4);
#pragma unroll
      for (int j = 0; j < 4; ++j) o[j] = f2b(v[j]);
    } else {
      int f = b * 2048 + (r - 16);
      int pr = (f >> 8) * 272 + 16 + (f & 255);
      o = *(const s16x4*)(Pout + (size_t)pr * 1024 + t * 4);
    }
    *(s16x4*)(&Xin[(size_t)row * 1024 + t * 4]) = o;
  } else {
    int m = row - 4352;
    int pr = (m >> 4) * 272 + (m & 15);
    s16x4 v = *(const s16x4*)(Pout + (size_t)pr * 1024 + t * 4);
    f32x4 o;
#pragma unroll
    for (int j = 0; j < 4; ++j) o[j] = b2f(v[j]);
    *(f32x4*)(&lm_out[(size_t)m * 1024 + t * 4]) = o;
  }
}

__global__ __launch_bounds__(256) void split_global_build_xl(const short* __restrict__ Pout,
                                                             const float* __restrict__ lm_src,
                                                             float* __restrict__ mem_out,
                                                             short* __restrict__ Xin) {
  int row = blockIdx.x;
  int t = threadIdx.x;
  if (row < 4352) {
    int s = row / 272, r = row % 272;
    s16x4 o;
    if (r < 16) {
      f32x4 v = *(const f32x4*)(lm_src + ((size_t)(s * 16 + r)) * 1024 + t * 4);
#pragma unroll
      for (int j = 0; j < 4; ++j) o[j] = f2b(v[j]);
    } else {
      int f = s * 256 + (r - 16);
      int pr = (f >> 11) * 2064 + 16 + (f & 2047);
      o = *(const s16x4*)(Pout + (size_t)pr * 1024 + t * 4);
    }
    *(s16x4*)(&Xin[(size_t)row * 1024 + t * 4]) = o;
  } else {
    int m = row - 4352;
    int pr = (m >> 4) * 2064 + (m & 15);
    s16x4 v = *(const s16x4*)(Pout + (size_t)pr * 1024 + t * 4);
    f32x4 o;
#pragma unroll
    for (int j = 0; j < 4; ++j) o[j] = b2f(v[j]);
    *(f32x4*)(&mem_out[(size_t)m * 1024 + t * 4]) = o;
  }
}

__global__ __launch_bounds__(256) void split_global_final(const short* __restrict__ Pout,
                                                          float* __restrict__ out) {
  int f = blockIdx.x;
  int t = threadIdx.x;
  int pr = (f >> 11) * 2064 + 16 + (f & 2047);
  s16x4 v = *(const s16x4*)(Pout + (size_t)pr * 1024 + t * 4);
  f32x4 o;
#pragma unroll
  for (int j = 0; j < 4; ++j) o[j] = b2f(v[j]);
  *(f32x4*)(&out[(size_t)f * 1024 + t * 4]) = o;
}

// ---------------- orchestration ----------------
extern "C" void kernel_launch(void* const* d_in, const int* in_sizes, int n_in,
                              void* d_out, int out_size, void* d_ws, size_t ws_size,
                              hipStream_t stream) {
  const float* x_in = (const float*)d_in[0];
  const float* mem_in = (const float*)d_in[1];
  const float* lm_in = (const float*)d_in[2];
  const float* Wqkv_loc = (const float*)d_in[3];
  const float* Wproj_loc = (const float*)d_in[4];
  const float* g_loc = (const float*)d_in[5];
  const float* Wqkv_glob = (const float*)d_in[6];
  const float* Wproj_glob = (const float*)d_in[7];
  const float* g_glob = (const float*)d_in[8];

  char* ws = (char*)d_ws;
  size_t off = 0;
  auto alloc = [&](size_t bytes) {
    char* p = ws + off;
    off += (bytes + 255) & ~(size_t)255;
    return p;
  };
  short* Wt = (short*)alloc((size_t)3072 * 1024 * 2);
  float* lm_cur = (float*)alloc((size_t)256 * 1024 * 4);
  float* mem_cur = (float*)alloc((size_t)32 * 1024 * 4);
  short* Xin = (short*)alloc((size_t)MPAD * 1024 * 2);
  short* QKVb = (short*)alloc((size_t)MPAD * 3072 * 2);
  short* Yb = (short*)alloc((size_t)MPAD * 1024 * 2);
  short* Pout = (short*)alloc((size_t)MPAD * 1024 * 2);
  short* Vtb = (short*)alloc((size_t)256 * 64 * 320 * 2);
  size_t oacc_bytes = (size_t)32 * LG * 64 * 4;
  size_t lacc_bytes = (size_t)32 * LG * 4;
  float* o_acc = (float*)alloc(oacc_bytes);
  float* ls_acc = (float*)alloc(lacc_bytes);
  const bool use_split = (ws_size >= off);

  for (int i = 0; i < 2; ++i) {
    // ---- local attention (16 seqs, L=272, rows = 4352 = MPAD) ----
    transpose_cast<<<dim3(96, 32), dim3(32, 8), 0, stream>>>(
        Wqkv_loc + (size_t)i * 1024 * 3072, Wt, 1024, 3072);
    if (i == 0) build_xl<<<4352, 256, 0, stream>>>(x_in, lm_in, Xin);
    gemm_bt3<<<dim3(24, 34), 256, 0, stream>>>(Xin, Wt, QKVb, 1024, 3072);
    rmsnorm_qk<<<dim3(4352, 2), 256, 0, stream>>>(QKVb, g_loc + (size_t)i * 1024);
    transpose_v<<<dim3(10, 2, 256), dim3(32, 8), 0, stream>>>(QKVb, Vtb, 272, 320);
    attn_causal3<<<dim3(5, 16, 16), 256, 0, stream>>>(QKVb, Vtb, Yb, 272, 320);
    transpose_cast<<<dim3(32, 32), dim3(32, 8), 0, stream>>>(
        Wproj_loc + (size_t)i * 1024 * 1024, Wt, 1024, 1024);
    gemm_bt3<<<dim3(8, 34), 256, 0, stream>>>(Yb, Wt, Pout, 1024, 1024);
    split_local_build_xg<<<4608, 256, 0, stream>>>(Pout, i == 0 ? mem_in : mem_cur,
                                                   lm_cur, Xin);

    // ---- global attention (2 seqs, L=2064, rows = 4128; pads deterministic) ----
    transpose_cast<<<dim3(96, 32), dim3(32, 8), 0, stream>>>(
        Wqkv_glob + (size_t)i * 1024 * 3072, Wt, 1024, 3072);
    gemm_bt3<<<dim3(24, 34), 256, 0, stream>>>(Xin, Wt, QKVb, 1024, 3072);
    rmsnorm_qk<<<dim3(4128, 2), 256, 0, stream>>>(QKVb, g_glob + (size_t)i * 1024);
    transpose_v<<<dim3(66, 2, 32), dim3(32, 8), 0, stream>>>(QKVb, Vtb, 2064, 2112);
    if (use_split) {
      hipMemsetAsync(o_acc, 0, oacc_bytes, stream);
      hipMemsetAsync(ls_acc, 0, lacc_bytes, stream);
      attn_split<<<dim3(33, 5, 32), 256, 0, stream>>>(QKVb, Vtb, o_acc, ls_acc);
      attn_merge<<<dim3(516, 16, 2), 256, 0, stream>>>(o_acc, ls_acc, Yb);
    } else {
      attn_causal3<<<dim3(33, 16, 2), 256, 0, stream>>>(QKVb, Vtb, Yb, 2064, 2112);
    }
    transpose_cast<<<dim3(32, 32), dim3(32, 8), 0, stream>>>(
        Wproj_glob + (size_t)i * 1024 * 1024, Wt, 1024, 1024);
    gemm_bt3<<<dim3(8, 34), 256, 0, stream>>>(Yb, Wt, Pout, 1024, 1024);
    if (i == 0)
      split_global_build_xl<<<4384, 256, 0, stream>>>(Pout, lm_cur, mem_cur, Xin);
    else
      split_global_final<<<4096, 256, 0, stream>>>(Pout, (float*)d_out);
  }
}

// Round 11
// 590.164 us; speedup vs baseline: 1.1112x; 1.0055x over previous
//
#include <hip/hip_runtime.h>
#include <hip/hip_bf16.h>
#include <math.h>

typedef __attribute__((ext_vector_type(8))) short s16x8;
typedef __attribute__((ext_vector_type(4))) short s16x4;
typedef __attribute__((ext_vector_type(4))) float f32x4;

#define MPAD 4352   // = 34*128
#define LG 2064     // global seq length
#define CT 8        // k-tiles (of 64 keys) per split chunk
#define SM_SHIFT 11.5415603f  // 8 * log2(e); softmax = exp2(S*log2e - SM_SHIFT)

__device__ __forceinline__ short f2b(float f) {  // RNE (weights/activations)
  unsigned u = __float_as_uint(f);
  unsigned r = (u + 0x7fffu + ((u >> 16) & 1u)) >> 16;
  return (short)(unsigned short)r;
}
__device__ __forceinline__ float b2f(short s) {
  return __uint_as_float(((unsigned)(unsigned short)s) << 16);
}
// raw v_exp_f32 (1 inst; libm exp2f carries a denormal-guard sequence)
__device__ __forceinline__ float fexp2(float x) {
#if __has_builtin(__builtin_amdgcn_exp2f)
  return __builtin_amdgcn_exp2f(x);
#else
  float r;
  asm("v_exp_f32 %0, %1" : "=v"(r) : "v"(x));
  return r;
#endif
}
// pack two f32 -> bf16x2 word (RNE), 1 inst
__device__ __forceinline__ int cvtpk(float lo, float hi) {
  int r;
  asm("v_cvt_pk_bf16_f32 %0, %1, %2" : "=v"(r) : "v"(lo), "v"(hi));
  return r;
}

// global->LDS direct async copy, 16B per lane. LDS dest must be uniform-base + lane*16.
__device__ __forceinline__ void gl_lds16(const short* g, short* l) {
  __builtin_amdgcn_global_load_lds((const __attribute__((address_space(1))) short*)g,
                                   (__attribute__((address_space(3))) short*)l, 16, 0, 0);
}

// ---------------- transpose + cast: in f32 (K x N) -> out bf16 (N x K) ----------------
__global__ __launch_bounds__(256) void transpose_cast(const float* __restrict__ in,
                                                      short* __restrict__ out,
                                                      int K, int N) {
  __shared__ float tile[32][33];
  int bn = blockIdx.x * 32;
  int bk = blockIdx.y * 32;
  for (int i = threadIdx.y; i < 32; i += 8)
    tile[i][threadIdx.x] = in[(size_t)(bk + i) * N + bn + threadIdx.x];
  __syncthreads();
  for (int i = threadIdx.y; i < 32; i += 8)
    out[(size_t)(bn + i) * K + bk + threadIdx.x] = f2b(tile[threadIdx.x][i]);
}

// ---------------- V transpose: QKV V-slice -> Vt[s*16+h][64][Lpad]; covers FULL Lpad ----------------
__global__ __launch_bounds__(256) void transpose_v(const short* __restrict__ QKV,
                                                   short* __restrict__ Vt,
                                                   int L, int Lpad) {
  __shared__ short tile[32][33];
  int sh = blockIdx.z;
  int s = sh >> 4, h = sh & 15;
  int kb = blockIdx.x * 32;
  int cb = blockIdx.y * 32;
  int tx = threadIdx.x;
  for (int i = threadIdx.y; i < 32; i += 8) {
    int key = kb + i;
    if (key > L - 1) key = L - 1;
    tile[i][tx] = QKV[(size_t)(s * L + key) * 3072 + 2048 + h * 64 + cb + tx];
  }
  __syncthreads();
  for (int i = threadIdx.y; i < 32; i += 8)
    Vt[((size_t)sh * 64 + cb + i) * Lpad + kb + tx] = tile[tx][i];
}

// ---------------- GEMM v3: 2-phase prefetch, gl_lds dbuf, 1 barrier/iter ----------------
__global__ __launch_bounds__(256) void gemm_bt3(const short* __restrict__ A,
                                                const short* __restrict__ BT,
                                                short* __restrict__ C,
                                                int K, int N) {
  __shared__ short As[2][128 * 32];
  __shared__ short Bs[2][128 * 32];
  const int tid = threadIdx.x;
  const int lane = tid & 63;
  const int w = tid >> 6;
  const int wr = (w >> 1) * 64, wc = (w & 1) * 64;
  const int m0 = blockIdx.y * 128;
  const int n0 = blockIdx.x * 128;
  const int l15 = lane & 15, lhi = lane >> 4;

  f32x4 acc[4][4] = {};

  auto STAGE = [&](int b, int k0) {
#pragma unroll
    for (int p = 0; p < 2; ++p) {
      int g = w * 128 + p * 64 + lane;
      int row = g >> 2;
      int cs = (g & 3) * 8;
      gl_lds16(A + (size_t)(m0 + row) * K + k0 + cs, &As[b][g * 8]);
      gl_lds16(BT + (size_t)(n0 + row) * K + k0 + cs, &Bs[b][g * 8]);
    }
  };

  const int nt = K >> 5;
  STAGE(0, 0);
  __syncthreads();
  int cur = 0;
  for (int t = 0; t < nt; ++t) {
    if (t + 1 < nt) STAGE(cur ^ 1, (t + 1) << 5);
    s16x8 af[4], bf[4];
#pragma unroll
    for (int m = 0; m < 4; ++m)
      af[m] = *(const s16x8*)(&As[cur][(wr + m * 16 + l15) * 32 + lhi * 8]);
#pragma unroll
    for (int n = 0; n < 4; ++n)
      bf[n] = *(const s16x8*)(&Bs[cur][(wc + n * 16 + l15) * 32 + lhi * 8]);
#pragma unroll
    for (int m = 0; m < 4; ++m)
#pragma unroll
      for (int n = 0; n < 4; ++n)
        acc[m][n] = __builtin_amdgcn_mfma_f32_16x16x32_bf16(af[m], bf[n], acc[m][n], 0, 0, 0);
    __syncthreads();
    cur ^= 1;
  }
#pragma unroll
  for (int m = 0; m < 4; ++m) {
    int row_base = m0 + wr + m * 16 + lhi * 4;
#pragma unroll
    for (int n = 0; n < 4; ++n) {
      int col = n0 + wc + n * 16 + l15;
#pragma unroll
      for (int r = 0; r < 4; ++r)
        C[(size_t)(row_base + r) * N + col] = f2b(acc[m][n][r]);
    }
  }
}

// ---------------- RMSNorm on Q (with 1/8*log2e scale) and K slices of QKV, in place ----------------
__global__ __launch_bounds__(256) void rmsnorm_qk(short* __restrict__ QKV,
                                                  const float* __restrict__ g) {
  int row = blockIdx.x;
  int which = blockIdx.y;  // 0 = q, 1 = k
  size_t base = (size_t)row * 3072 + (size_t)which * 1024;
  int t = threadIdx.x;
  s16x4 in = *(const s16x4*)(QKV + base + t * 4);
  float v[4];
  float ss = 0.f;
#pragma unroll
  for (int j = 0; j < 4; ++j) {
    v[j] = b2f(in[j]);
    ss += v[j] * v[j];
  }
#pragma unroll
  for (int m = 32; m >= 1; m >>= 1) ss += __shfl_xor(ss, m);
  __shared__ float red[4];
  if ((t & 63) == 0) red[t >> 6] = ss;
  __syncthreads();
  float tot = red[0] + red[1] + red[2] + red[3];
  float inv = rsqrtf(tot * (1.0f / 1024.0f) + 1e-6f);
  if (which == 0) inv *= 0.125f * 1.44269504f;  // fold 1/sqrt(hd) AND log2(e) into Q
  s16x4 out;
#pragma unroll
  for (int j = 0; j < 4; ++j) out[j] = f2b(v[j] * inv * g[t * 4 + j]);
  *(s16x4*)(&QKV[base + t * 4]) = out;
}

// ======== swapped-operand attention core ========
// QK^T computed as mfma(K, Q) => lane (l15,lhi) holds P^T[key = kb+n*16+lhi*4+r][q = q0+w*16+l15].
// P -> bf16 via v_cvt_pk (key-pairs are lane-local), PV A-fragment assembled by 16 __shfl.
// PV = mfma(pa, vf): identical lane mappings to before => output layout UNCHANGED.
// One barrier per tile-iter (Ks AND Vs double-buffered); prefetch issued AFTER the barrier
// so the global loads stay in flight across the compute phase (the compiler drains vmcnt at
// barriers, so pre-barrier "prefetch" never overlapped).

// ---------------- causal flash attention (local) ----------------
__global__ __launch_bounds__(256) void attn_causal4(const short* __restrict__ QKV,
                                                    const short* __restrict__ Vt,
                                                    short* __restrict__ Y,
                                                    int L, int Lpad) {
  const int h = blockIdx.y, s = blockIdx.z;
  const int q0 = blockIdx.x * 64;
  const int tid = threadIdx.x;
  const int lane = tid & 63, w = tid >> 6;
  const int l15 = lane & 15, lhi = lane >> 4;
  const int row0 = s * L;

  __shared__ short Ks[2][64][72];
  __shared__ short Vs[2][64][72];

  int qld = q0 + w * 16 + l15;
  if (qld > L - 1) qld = L - 1;
  const size_t qrow = (size_t)(row0 + qld) * 3072 + h * 64;
  s16x8 qf0 = *(const s16x8*)(QKV + qrow + lhi * 8);
  s16x8 qf1 = *(const s16x8*)(QKV + qrow + 32 + lhi * 8);

  float lsum = 0.f;
  f32x4 o[4];
#pragma unroll
  for (int d = 0; d < 4; ++d) o[d] = f32x4{0.f, 0.f, 0.f, 0.f};

  const short* Vbase = Vt + (size_t)(s * 16 + h) * 64 * Lpad;
  const int sA = (lhi & 1) * 32 + l15;  // shfl source lanes for PV fragment
  const int sB = sA + 16;
  const int bh = lhi >> 1;

  s16x8 kreg[2], vreg[2];
#pragma unroll
  for (int p = 0; p < 2; ++p) {
    int g = tid + p * 256;
    int kr = g >> 3, cs = (g & 7) * 8;
    int krow = kr;
    if (krow > L - 1) krow = L - 1;
    kreg[p] = *(const s16x8*)(QKV + (size_t)(row0 + krow) * 3072 + 1024 + h * 64 + cs);
    vreg[p] = *(const s16x8*)(Vbase + (size_t)kr * Lpad + cs);
  }

  int buf = 0;
  for (int kb = 0; kb <= q0; kb += 64, buf ^= 1) {
#pragma unroll
    for (int p = 0; p < 2; ++p) {
      int g = tid + p * 256;
      int kr = g >> 3, cs = (g & 7) * 8;
      *(s16x8*)(&Ks[buf][kr][cs]) = kreg[p];
      *(s16x8*)(&Vs[buf][kr][cs]) = vreg[p];
    }
    __syncthreads();
    if (kb + 64 <= q0) {  // prefetch AFTER barrier: in flight across compute
#pragma unroll
      for (int p = 0; p < 2; ++p) {
        int g = tid + p * 256;
        int kr = g >> 3, cs = (g & 7) * 8;
        int krow = kb + 64 + kr;
        if (krow > L - 1) krow = L - 1;
        kreg[p] = *(const s16x8*)(QKV + (size_t)(row0 + krow) * 3072 + 1024 + h * 64 + cs);
        vreg[p] = *(const s16x8*)(Vbase + (size_t)kr * Lpad + kb + 64 + cs);
      }
    }

    // S^T = K Q^T (swapped operands)
    f32x4 st[4];
#pragma unroll
    for (int n = 0; n < 4; ++n) {
      s16x8 k0 = *(const s16x8*)(&Ks[buf][n * 16 + l15][lhi * 8]);
      s16x8 k1 = *(const s16x8*)(&Ks[buf][n * 16 + l15][32 + lhi * 8]);
      f32x4 sa = f32x4{-SM_SHIFT, -SM_SHIFT, -SM_SHIFT, -SM_SHIFT};
      sa = __builtin_amdgcn_mfma_f32_16x16x32_bf16(k0, qf0, sa, 0, 0, 0);
      sa = __builtin_amdgcn_mfma_f32_16x16x32_bf16(k1, qf1, sa, 0, 0, 0);
      st[n] = sa;
    }

    if (kb == q0) {  // diagonal tile mask: key > q
      int q = q0 + w * 16 + l15;
#pragma unroll
      for (int n = 0; n < 4; ++n) {
#pragma unroll
        for (int r = 0; r < 4; ++r) {
          int key = kb + n * 16 + lhi * 4 + r;
          if (key > q) st[n][r] = -1e30f;
        }
      }
    }

    int wd[4][2];
#pragma unroll
    for (int n = 0; n < 4; ++n) {
      float p0 = fexp2(st[n][0]), p1 = fexp2(st[n][1]);
      float p2 = fexp2(st[n][2]), p3 = fexp2(st[n][3]);
      lsum += (p0 + p1) + (p2 + p3);
      wd[n][0] = cvtpk(p0, p1);
      wd[n][1] = cvtpk(p2, p3);
    }

#pragma unroll
    for (int kk = 0; kk < 2; ++kk) {
      int a0 = __shfl(wd[2 * kk][0], sA), a1 = __shfl(wd[2 * kk][1], sA);
      int a2 = __shfl(wd[2 * kk][0], sB), a3 = __shfl(wd[2 * kk][1], sB);
      int b0 = __shfl(wd[2 * kk + 1][0], sA), b1 = __shfl(wd[2 * kk + 1][1], sA);
      int b2 = __shfl(wd[2 * kk + 1][0], sB), b3 = __shfl(wd[2 * kk + 1][1], sB);
      int pw[4];
      pw[0] = bh ? b0 : a0;
      pw[1] = bh ? b1 : a1;
      pw[2] = bh ? b2 : a2;
      pw[3] = bh ? b3 : a3;
      s16x8 pa = *(const s16x8*)pw;
#pragma unroll
      for (int d = 0; d < 4; ++d) {
        s16x8 vf = *(const s16x8*)(&Vs[buf][d * 16 + l15][kk * 32 + lhi * 8]);
        o[d] = __builtin_amdgcn_mfma_f32_16x16x32_bf16(pa, vf, o[d], 0, 0, 0);
      }
    }
  }

  // full row-sum for q = q0+w*16+l15, then redistribute to output rows q0+w*16+lhi*4+r
  lsum += __shfl_xor(lsum, 16);
  lsum += __shfl_xor(lsum, 32);
  float lsq[4];
#pragma unroll
  for (int r = 0; r < 4; ++r) lsq[r] = __shfl(lsum, lhi * 4 + r);
#pragma unroll
  for (int d = 0; d < 4; ++d) {
#pragma unroll
    for (int r = 0; r < 4; ++r) {
      int qr = q0 + w * 16 + lhi * 4 + r;
      if (qr < L)
        Y[(size_t)(row0 + qr) * 1024 + h * 64 + d * 16 + l15] = f2b(o[d][r] / lsq[r]);
    }
  }
}

// ---------------- split-K causal attention (global, L=2064) ----------------
__global__ __launch_bounds__(256) void attn_split2(const short* __restrict__ QKV,
                                                   const short* __restrict__ Vt,
                                                   float* __restrict__ o_acc,
                                                   float* __restrict__ ls_acc) {
  const int qb = blockIdx.x;
  const int chunk = blockIdx.y;
  const int sh = blockIdx.z;
  const int t0 = chunk * CT;
  if (t0 > qb) return;
  const int t1 = min(t0 + CT, qb + 1);
  const int h = sh & 15, s = sh >> 4;
  const int q0 = qb * 64;
  const int tid = threadIdx.x;
  const int lane = tid & 63, w = tid >> 6;
  const int l15 = lane & 15, lhi = lane >> 4;
  const int row0 = s * LG;
  const int Lpad = 2112;

  __shared__ short Ks[2][64][72];
  __shared__ short Vs[2][64][72];

  int qld = q0 + w * 16 + l15;
  if (qld > LG - 1) qld = LG - 1;
  const size_t qrow = (size_t)(row0 + qld) * 3072 + h * 64;
  s16x8 qf0 = *(const s16x8*)(QKV + qrow + lhi * 8);
  s16x8 qf1 = *(const s16x8*)(QKV + qrow + 32 + lhi * 8);

  float lsum = 0.f;
  f32x4 o[4];
#pragma unroll
  for (int d = 0; d < 4; ++d) o[d] = f32x4{0.f, 0.f, 0.f, 0.f};

  const short* Vbase = Vt + (size_t)sh * 64 * Lpad;
  const int sA = (lhi & 1) * 32 + l15;
  const int sB = sA + 16;
  const int bh = lhi >> 1;

  s16x8 kreg[2], vreg[2];
  const int kb0 = t0 * 64;
#pragma unroll
  for (int p = 0; p < 2; ++p) {
    int g = tid + p * 256;
    int kr = g >> 3, cs = (g & 7) * 8;
    int krow = kb0 + kr;
    if (krow > LG - 1) krow = LG - 1;
    kreg[p] = *(const s16x8*)(QKV + (size_t)(row0 + krow) * 3072 + 1024 + h * 64 + cs);
    vreg[p] = *(const s16x8*)(Vbase + (size_t)kr * Lpad + kb0 + cs);
  }

  int buf = 0;
  for (int t = t0; t < t1; ++t, buf ^= 1) {
    const int kb = t * 64;
#pragma unroll
    for (int p = 0; p < 2; ++p) {
      int g = tid + p * 256;
      int kr = g >> 3, cs = (g & 7) * 8;
      *(s16x8*)(&Ks[buf][kr][cs]) = kreg[p];
      *(s16x8*)(&Vs[buf][kr][cs]) = vreg[p];
    }
    __syncthreads();
    if (t + 1 < t1) {  // prefetch AFTER barrier
#pragma unroll
      for (int p = 0; p < 2; ++p) {
        int g = tid + p * 256;
        int kr = g >> 3, cs = (g & 7) * 8;
        int krow = kb + 64 + kr;
        if (krow > LG - 1) krow = LG - 1;
        kreg[p] = *(const s16x8*)(QKV + (size_t)(row0 + krow) * 3072 + 1024 + h * 64 + cs);
        vreg[p] = *(const s16x8*)(Vbase + (size_t)kr * Lpad + kb + 64 + cs);
      }
    }

    f32x4 st[4];
#pragma unroll
    for (int n = 0; n < 4; ++n) {
      s16x8 k0 = *(const s16x8*)(&Ks[buf][n * 16 + l15][lhi * 8]);
      s16x8 k1 = *(const s16x8*)(&Ks[buf][n * 16 + l15][32 + lhi * 8]);
      f32x4 sa = f32x4{-SM_SHIFT, -SM_SHIFT, -SM_SHIFT, -SM_SHIFT};
      sa = __builtin_amdgcn_mfma_f32_16x16x32_bf16(k0, qf0, sa, 0, 0, 0);
      sa = __builtin_amdgcn_mfma_f32_16x16x32_bf16(k1, qf1, sa, 0, 0, 0);
      st[n] = sa;
    }

    if (t == qb) {  // diagonal tile mask
      int q = q0 + w * 16 + l15;
#pragma unroll
      for (int n = 0; n < 4; ++n) {
#pragma unroll
        for (int r = 0; r < 4; ++r) {
          int key = kb + n * 16 + lhi * 4 + r;
          if (key > q) st[n][r] = -1e30f;
        }
      }
    }

    int wd[4][2];
#pragma unroll
    for (int n = 0; n < 4; ++n) {
      float p0 = fexp2(st[n][0]), p1 = fexp2(st[n][1]);
      float p2 = fexp2(st[n][2]), p3 = fexp2(st[n][3]);
      lsum += (p0 + p1) + (p2 + p3);
      wd[n][0] = cvtpk(p0, p1);
      wd[n][1] = cvtpk(p2, p3);
    }

#pragma unroll
    for (int kk = 0; kk < 2; ++kk) {
      int a0 = __shfl(wd[2 * kk][0], sA), a1 = __shfl(wd[2 * kk][1], sA);
      int a2 = __shfl(wd[2 * kk][0], sB), a3 = __shfl(wd[2 * kk][1], sB);
      int b0 = __shfl(wd[2 * kk + 1][0], sA), b1 = __shfl(wd[2 * kk + 1][1], sA);
      int b2 = __shfl(wd[2 * kk + 1][0], sB), b3 = __shfl(wd[2 * kk + 1][1], sB);
      int pw[4];
      pw[0] = bh ? b0 : a0;
      pw[1] = bh ? b1 : a1;
      pw[2] = bh ? b2 : a2;
      pw[3] = bh ? b3 : a3;
      s16x8 pa = *(const s16x8*)pw;
#pragma unroll
      for (int d = 0; d < 4; ++d) {
        s16x8 vf = *(const s16x8*)(&Vs[buf][d * 16 + l15][kk * 32 + lhi * 8]);
        o[d] = __builtin_amdgcn_mfma_f32_16x16x32_bf16(pa, vf, o[d], 0, 0, 0);
      }
    }
  }

  // lsum is per-lane partial for q = q0+w*16+l15; reduce over lhi groups
  lsum += __shfl_xor(lsum, 16);
  lsum += __shfl_xor(lsum, 32);
  int qmy = q0 + w * 16 + l15;
  if (lhi == 0 && qmy < LG) atomicAdd(&ls_acc[(size_t)sh * LG + qmy], lsum);
#pragma unroll
  for (int r = 0; r < 4; ++r) {
    int qr = q0 + w * 16 + lhi * 4 + r;
    if (qr < LG) {
#pragma unroll
      for (int d = 0; d < 4; ++d)
        atomicAdd(&o_acc[((size_t)sh * LG + qr) * 64 + d * 16 + l15], o[d][r]);
    }
  }
}

// merge: Y = o_acc / ls_acc
__global__ __launch_bounds__(256) void attn_merge(const float* __restrict__ o_acc,
                                                  const float* __restrict__ ls_acc,
                                                  short* __restrict__ Y) {
  int sh = blockIdx.z * 16 + blockIdx.y;
  int s = sh >> 4, h = sh & 15;
  int row = blockIdx.x * 4 + (threadIdx.x >> 6);
  int col = threadIdx.x & 63;
  if (row < LG) {
    float inv = 1.0f / ls_acc[(size_t)sh * LG + row];
    float v = o_acc[((size_t)sh * LG + row) * 64 + col];
    Y[(size_t)(s * LG + row) * 1024 + h * 64 + col] = f2b(v * inv);
  }
}

// ---------------- fused gather/scatter ----------------
__global__ __launch_bounds__(256) void build_xl(const float* __restrict__ x,
                                                const float* __restrict__ lm,
                                                short* __restrict__ Xin) {
  int row = blockIdx.x;  // 0..4351
  int s = row / 272, r = row % 272;
  const float* src = (r < 16) ? lm + ((size_t)s * 16 + r) * 1024
                              : x + ((size_t)s * 256 + (r - 16)) * 1024;
  int t = threadIdx.x;
  f32x4 v = *(const f32x4*)(src + t * 4);
  s16x4 o;
#pragma unroll
  for (int j = 0; j < 4; ++j) o[j] = f2b(v[j]);
  *(s16x4*)(&Xin[(size_t)row * 1024 + t * 4]) = o;
}

__global__ __launch_bounds__(256) void split_local_build_xg(const short* __restrict__ Pout,
                                                            const float* __restrict__ mem_src,
                                                            float* __restrict__ lm_out,
                                                            short* __restrict__ Xin) {
  int row = blockIdx.x;
  int t = threadIdx.x;
  if (row < 4352) {
    int sr = row < 4128 ? row : 4127;
    int b = sr / 2064, r = sr % 2064;
    s16x4 o;
    if (r < 16) {
      f32x4 v = *(const f32x4*)(mem_src + ((size_t)(b * 16 + r)) * 1024 + t * 4);
#pragma unroll
      for (int j = 0; j < 4; ++j) o[j] = f2b(v[j]);
    } else {
      int f = b * 2048 + (r - 16);
      int pr = (f >> 8) * 272 + 16 + (f & 255);
      o = *(const s16x4*)(Pout + (size_t)pr * 1024 + t * 4);
    }
    *(s16x4*)(&Xin[(size_t)row * 1024 + t * 4]) = o;
  } else {
    int m = row - 4352;
    int pr = (m >> 4) * 272 + (m & 15);
    s16x4 v = *(const s16x4*)(Pout + (size_t)pr * 1024 + t * 4);
    f32x4 o;
#pragma unroll
    for (int j = 0; j < 4; ++j) o[j] = b2f(v[j]);
    *(f32x4*)(&lm_out[(size_t)m * 1024 + t * 4]) = o;
  }
}

__global__ __launch_bounds__(256) void split_global_build_xl(const short* __restrict__ Pout,
                                                             const float* __restrict__ lm_src,
                                                             float* __restrict__ mem_out,
                                                             short* __restrict__ Xin) {
  int row = blockIdx.x;
  int t = threadIdx.x;
  if (row < 4352) {
    int s = row / 272, r = row % 272;
    s16x4 o;
    if (r < 16) {
      f32x4 v = *(const f32x4*)(lm_src + ((size_t)(s * 16 + r)) * 1024 + t * 4);
#pragma unroll
      for (int j = 0; j < 4; ++j) o[j] = f2b(v[j]);
    } else {
      int f = s * 256 + (r - 16);
      int pr = (f >> 11) * 2064 + 16 + (f & 2047);
      o = *(const s16x4*)(Pout + (size_t)pr * 1024 + t * 4);
    }
    *(s16x4*)(&Xin[(size_t)row * 1024 + t * 4]) = o;
  } else {
    int m = row - 4352;
    int pr = (m >> 4) * 2064 + (m & 15);
    s16x4 v = *(const s16x4*)(Pout + (size_t)pr * 1024 + t * 4);
    f32x4 o;
#pragma unroll
    for (int j = 0; j < 4; ++j) o[j] = b2f(v[j]);
    *(f32x4*)(&mem_out[(size_t)m * 1024 + t * 4]) = o;
  }
}

__global__ __launch_bounds__(256) void split_global_final(const short* __restrict__ Pout,
                                                          float* __restrict__ out) {
  int f = blockIdx.x;
  int t = threadIdx.x;
  int pr = (f >> 11) * 2064 + 16 + (f & 2047);
  s16x4 v = *(const s16x4*)(Pout + (size_t)pr * 1024 + t * 4);
  f32x4 o;
#pragma unroll
  for (int j = 0; j < 4; ++j) o[j] = b2f(v[j]);
  *(f32x4*)(&out[(size_t)f * 1024 + t * 4]) = o;
}

// ---------------- orchestration ----------------
extern "C" void kernel_launch(void* const* d_in, const int* in_sizes, int n_in,
                              void* d_out, int out_size, void* d_ws, size_t ws_size,
                              hipStream_t stream) {
  const float* x_in = (const float*)d_in[0];
  const float* mem_in = (const float*)d_in[1];
  const float* lm_in = (const float*)d_in[2];
  const float* Wqkv_loc = (const float*)d_in[3];
  const float* Wproj_loc = (const float*)d_in[4];
  const float* g_loc = (const float*)d_in[5];
  const float* Wqkv_glob = (const float*)d_in[6];
  const float* Wproj_glob = (const float*)d_in[7];
  const float* g_glob = (const float*)d_in[8];

  char* ws = (char*)d_ws;
  size_t off = 0;
  auto alloc = [&](size_t bytes) {
    char* p = ws + off;
    off += (bytes + 255) & ~(size_t)255;
    return p;
  };
  short* Wt = (short*)alloc((size_t)3072 * 1024 * 2);
  float* lm_cur = (float*)alloc((size_t)256 * 1024 * 4);
  float* mem_cur = (float*)alloc((size_t)32 * 1024 * 4);
  short* Xin = (short*)alloc((size_t)MPAD * 1024 * 2);
  short* QKVb = (short*)alloc((size_t)MPAD * 3072 * 2);
  short* Yb = (short*)alloc((size_t)MPAD * 1024 * 2);
  short* Pout = (short*)alloc((size_t)MPAD * 1024 * 2);
  short* Vtb = (short*)alloc((size_t)256 * 64 * 320 * 2);
  size_t oacc_bytes = (size_t)32 * LG * 64 * 4;
  size_t lacc_bytes = (size_t)32 * LG * 4;
  float* o_acc = (float*)alloc(oacc_bytes);
  float* ls_acc = (float*)alloc(lacc_bytes);
  const bool use_split = (ws_size >= off);

  for (int i = 0; i < 2; ++i) {
    // ---- local attention (16 seqs, L=272, rows = 4352 = MPAD) ----
    transpose_cast<<<dim3(96, 32), dim3(32, 8), 0, stream>>>(
        Wqkv_loc + (size_t)i * 1024 * 3072, Wt, 1024, 3072);
    if (i == 0) build_xl<<<4352, 256, 0, stream>>>(x_in, lm_in, Xin);
    gemm_bt3<<<dim3(24, 34), 256, 0, stream>>>(Xin, Wt, QKVb, 1024, 3072);
    rmsnorm_qk<<<dim3(4352, 2), 256, 0, stream>>>(QKVb, g_loc + (size_t)i * 1024);
    transpose_v<<<dim3(10, 2, 256), dim3(32, 8), 0, stream>>>(QKVb, Vtb, 272, 320);
    attn_causal4<<<dim3(5, 16, 16), 256, 0, stream>>>(QKVb, Vtb, Yb, 272, 320);
    transpose_cast<<<dim3(32, 32), dim3(32, 8), 0, stream>>>(
        Wproj_loc + (size_t)i * 1024 * 1024, Wt, 1024, 1024);
    gemm_bt3<<<dim3(8, 34), 256, 0, stream>>>(Yb, Wt, Pout, 1024, 1024);
    split_local_build_xg<<<4608, 256, 0, stream>>>(Pout, i == 0 ? mem_in : mem_cur,
                                                   lm_cur, Xin);

    // ---- global attention (2 seqs, L=2064, rows = 4128; pads deterministic) ----
    transpose_cast<<<dim3(96, 32), dim3(32, 8), 0, stream>>>(
        Wqkv_glob + (size_t)i * 1024 * 3072, Wt, 1024, 3072);
    gemm_bt3<<<dim3(24, 34), 256, 0, stream>>>(Xin, Wt, QKVb, 1024, 3072);
    rmsnorm_qk<<<dim3(4128, 2), 256, 0, stream>>>(QKVb, g_glob + (size_t)i * 1024);
    transpose_v<<<dim3(66, 2, 32), dim3(32, 8), 0, stream>>>(QKVb, Vtb, 2064, 2112);
    if (use_split) {
      hipMemsetAsync(o_acc, 0, oacc_bytes, stream);
      hipMemsetAsync(ls_acc, 0, lacc_bytes, stream);
      attn_split2<<<dim3(33, 5, 32), 256, 0, stream>>>(QKVb, Vtb, o_acc, ls_acc);
      attn_merge<<<dim3(516, 16, 2), 256, 0, stream>>>(o_acc, ls_acc, Yb);
    } else {
      attn_causal4<<<dim3(33, 16, 2), 256, 0, stream>>>(QKVb, Vtb, Yb, 2064, 2112);
    }
    transpose_cast<<<dim3(32, 32), dim3(32, 8), 0, stream>>>(
        Wproj_glob + (size_t)i * 1024 * 1024, Wt, 1024, 1024);
    gemm_bt3<<<dim3(8, 34), 256, 0, stream>>>(Yb, Wt, Pout, 1024, 1024);
    if (i == 0)
      split_global_build_xl<<<4384, 256, 0, stream>>>(Pout, lm_cur, mem_cur, Xin);
    else
      split_global_final<<<4096, 256, 0, stream>>>(Pout, (float*)d_out);
  }
}

// Round 12
// 529.575 us; speedup vs baseline: 1.2383x; 1.1144x over previous
//
#include <hip/hip_runtime.h>
#include <hip/hip_bf16.h>
#include <math.h>

typedef __attribute__((ext_vector_type(8))) short s16x8;
typedef __attribute__((ext_vector_type(4))) short s16x4;
typedef __attribute__((ext_vector_type(4))) float f32x4;

#define MPAD 4352   // = 34*128 = 17*256
#define LG 2064     // global seq length
#define CT 8        // k-tiles (of 64 keys) per split chunk
#define SM_SHIFT 11.5415603f  // 8 * log2(e); softmax = exp2(S*log2e - SM_SHIFT)

__device__ __forceinline__ short f2b(float f) {  // RNE (weights/activations)
  unsigned u = __float_as_uint(f);
  unsigned r = (u + 0x7fffu + ((u >> 16) & 1u)) >> 16;
  return (short)(unsigned short)r;
}
__device__ __forceinline__ float b2f(short s) {
  return __uint_as_float(((unsigned)(unsigned short)s) << 16);
}
__device__ __forceinline__ float fexp2(float x) {
#if __has_builtin(__builtin_amdgcn_exp2f)
  return __builtin_amdgcn_exp2f(x);
#else
  float r;
  asm("v_exp_f32 %0, %1" : "=v"(r) : "v"(x));
  return r;
#endif
}
__device__ __forceinline__ int cvtpk(float lo, float hi) {
  int r;
  asm("v_cvt_pk_bf16_f32 %0, %1, %2" : "=v"(r) : "v"(lo), "v"(hi));
  return r;
}

// global->LDS direct async copy, 16B per lane. LDS dest must be uniform-base + lane*16.
__device__ __forceinline__ void gl_lds16(const short* g, short* l) {
  __builtin_amdgcn_global_load_lds((const __attribute__((address_space(1))) short*)g,
                                   (__attribute__((address_space(3))) short*)l, 16, 0, 0);
}

// ---------------- transpose + cast: in f32 (K x N) -> out bf16 (N x K) ----------------
__global__ __launch_bounds__(256) void transpose_cast(const float* __restrict__ in,
                                                      short* __restrict__ out,
                                                      int K, int N) {
  __shared__ float tile[32][33];
  int bn = blockIdx.x * 32;
  int bk = blockIdx.y * 32;
  for (int i = threadIdx.y; i < 32; i += 8)
    tile[i][threadIdx.x] = in[(size_t)(bk + i) * N + bn + threadIdx.x];
  __syncthreads();
  for (int i = threadIdx.y; i < 32; i += 8)
    out[(size_t)(bn + i) * K + bk + threadIdx.x] = f2b(tile[threadIdx.x][i]);
}

// ---------------- V transpose: QKV V-slice -> Vt[s*16+h][64][Lpad]; covers FULL Lpad ----------------
__global__ __launch_bounds__(256) void transpose_v(const short* __restrict__ QKV,
                                                   short* __restrict__ Vt,
                                                   int L, int Lpad) {
  __shared__ short tile[32][33];
  int sh = blockIdx.z;
  int s = sh >> 4, h = sh & 15;
  int kb = blockIdx.x * 32;
  int cb = blockIdx.y * 32;
  int tx = threadIdx.x;
  for (int i = threadIdx.y; i < 32; i += 8) {
    int key = kb + i;
    if (key > L - 1) key = L - 1;
    tile[i][tx] = QKV[(size_t)(s * L + key) * 3072 + 2048 + h * 64 + cb + tx];
  }
  __syncthreads();
  for (int i = threadIdx.y; i < 32; i += 8)
    Vt[((size_t)sh * 64 + cb + i) * Lpad + kb + tx] = tile[tx][i];
}

// ================= 8-phase 256x256 GEMM (T3+T4 counted vmcnt, T2 swizzle, T5 setprio) ============
// C[M x N] = A[M x K] * BT[N x K]^T, bf16 in/out. Requires M%256==0, N%256==0, K%128==0.
// 8 waves (2M x 4N), BK=64, 2 K-tiles/iteration, 8 phases/iteration.
// LDS (dynamic, 128KB): A[2buf][2half][128][64], B[2buf][2half][128][64] bf16.
// Raw s_barrier (NOT __syncthreads: that drains vmcnt(0) and kills the pipeline).
// Swizzle: 16B-slot' = slot ^ (row&7), applied on the GLOBAL source (gl_lds dest linear,
// rule 21) and on the ds_read address -> each consecutive-8-lane group hits 8 distinct slots.
// vmcnt(4) at phases 3 and 7 (= one A-half-pair in flight); vmcnt(0) at phase 3 of last iter.
#define QROW(MI, AX)                                                                  \
  acc[MI][0] = __builtin_amdgcn_mfma_f32_16x16x32_bf16(AX, b0, acc[MI][0], 0, 0, 0);  \
  acc[MI][1] = __builtin_amdgcn_mfma_f32_16x16x32_bf16(AX, b1, acc[MI][1], 0, 0, 0);  \
  acc[MI][2] = __builtin_amdgcn_mfma_f32_16x16x32_bf16(AX, b2, acc[MI][2], 0, 0, 0);  \
  acc[MI][3] = __builtin_amdgcn_mfma_f32_16x16x32_bf16(AX, b3, acc[MI][3], 0, 0, 0);

#define RD12(B, S)                                                              \
  a0 = rdA(B, S, 0); a1 = rdA(B, S, 1); a2 = rdA(B, S, 2); a3 = rdA(B, S, 3);   \
  a4 = rdA(B, S, 4); a5 = rdA(B, S, 5); a6 = rdA(B, S, 6); a7 = rdA(B, S, 7);   \
  b0 = rdB(B, S, 0); b1 = rdB(B, S, 1); b2 = rdB(B, S, 2); b3 = rdB(B, S, 3);

__global__ __launch_bounds__(512, 2) void gemm_8ph(const short* __restrict__ A,
                                                   const short* __restrict__ BT,
                                                   short* __restrict__ C,
                                                   int K, int N) {
  extern __shared__ short lds[];      // 65536 shorts = 128KB
  short* Asb = lds;                   // [buf*2+half][8192]
  short* Bsb = lds + 32768;
  const int tid = threadIdx.x;
  const int lane = tid & 63, wid = tid >> 6;
  const int wm = wid >> 2, wn = wid & 3;  // 2 x 4 wave grid
  const int l15 = lane & 15, lhi = lane >> 4;
  const int m0 = blockIdx.y * 256;
  const int n0 = blockIdx.x * 256;

  f32x4 acc[8][4] = {};

  auto stageA = [&](int b, int h, int kt) {
#pragma unroll
    for (int j = 0; j < 2; ++j) {
      int u = j * 512 + tid;          // 0..1023
      int row = u >> 3, slot = u & 7;
      int ss = slot ^ (row & 7);      // inverse swizzle on source (involution)
      gl_lds16(A + (size_t)(m0 + h * 128 + row) * K + kt * 64 + ss * 8,
               Asb + (b * 2 + h) * 8192 + u * 8);
    }
  };
  auto stageB = [&](int b, int h, int kt) {
#pragma unroll
    for (int j = 0; j < 2; ++j) {
      int u = j * 512 + tid;
      int row = u >> 3, slot = u & 7;
      int ss = slot ^ (row & 7);
      gl_lds16(BT + (size_t)(n0 + h * 128 + row) * K + kt * 64 + ss * 8,
               Bsb + (b * 2 + h) * 8192 + u * 8);
    }
  };
  auto rdA = [&](int b, int s, int mf) -> s16x8 {
    int row = mf * 16 + l15;
    int sl = ((s << 2) | lhi) ^ (row & 7);
    return *(const s16x8*)(Asb + (b * 2 + wm) * 8192 + row * 64 + sl * 8);
  };
  auto rdB = [&](int b, int s, int nf) -> s16x8 {
    int row = (wn & 1) * 64 + nf * 16 + l15;
    int sl = ((s << 2) | lhi) ^ (row & 7);
    return *(const s16x8*)(Bsb + (b * 2 + (wn >> 1)) * 8192 + row * 64 + sl * 8);
  };

  const int NT = K >> 7;  // iterations; 2 K-tiles (BK=64) each

  // prologue: kt0 fully -> buf0; kt1 A-halves -> buf1 (kt1 B-halves staged at p0/p1 of iter 0)
  stageA(0, 0, 0); stageA(0, 1, 0); stageB(0, 0, 0); stageB(0, 1, 0);
  stageA(1, 0, 1); stageA(1, 1, 1);
  asm volatile("s_waitcnt vmcnt(4)" ::: "memory");  // kt0's 8 loads landed
  __builtin_amdgcn_s_barrier();

  s16x8 a0, a1, a2, a3, a4, a5, a6, a7, b0, b1, b2, b3;

  for (int t = 0; t < NT; ++t) {
    const bool last = (t == NT - 1);
    const int kt1 = 2 * t + 1;
    // p0: read buf0 s0 (12); stage Bh0(kt1)->buf1; MFMA m0-3 @ s0
    RD12(0, 0)
    stageB(1, 0, kt1);
    __builtin_amdgcn_s_barrier();
    __builtin_amdgcn_s_setprio(1);
    QROW(0, a0) QROW(1, a1) QROW(2, a2) QROW(3, a3)
    __builtin_amdgcn_s_setprio(0);
    __builtin_amdgcn_s_barrier();
    // p1: stage Bh1(kt1)->buf1; MFMA m4-7 @ s0
    stageB(1, 1, kt1);
    __builtin_amdgcn_s_barrier();
    __builtin_amdgcn_s_setprio(1);
    QROW(4, a4) QROW(5, a5) QROW(6, a6) QROW(7, a7)
    __builtin_amdgcn_s_setprio(0);
    __builtin_amdgcn_s_barrier();
    // p2: read buf0 s1 (12); MFMA m0-3 @ s1
    RD12(0, 1)
    __builtin_amdgcn_s_barrier();
    __builtin_amdgcn_s_setprio(1);
    QROW(0, a0) QROW(1, a1) QROW(2, a2) QROW(3, a3)
    __builtin_amdgcn_s_setprio(0);
    __builtin_amdgcn_s_barrier();
    // p3: stage A-halves(kt0+2)->buf0; counted vmcnt; MFMA m4-7 @ s1
    if (!last) {
      stageA(0, 0, 2 * t + 2); stageA(0, 1, 2 * t + 2);
      asm volatile("s_waitcnt vmcnt(4)" ::: "memory");  // kt1's A (prev p7) + B (p0,p1) landed
    } else {
      asm volatile("s_waitcnt vmcnt(0)" ::: "memory");  // final iter: drain (nothing to overlap)
    }
    __builtin_amdgcn_s_barrier();
    __builtin_amdgcn_s_setprio(1);
    QROW(4, a4) QROW(5, a5) QROW(6, a6) QROW(7, a7)
    __builtin_amdgcn_s_setprio(0);
    __builtin_amdgcn_s_barrier();
    // p4: read buf1 s0 (12); stage Bh0(kt0+2)->buf0; MFMA m0-3 @ kt1,s0
    RD12(1, 0)
    if (!last) stageB(0, 0, 2 * t + 2);
    __builtin_amdgcn_s_barrier();
    __builtin_amdgcn_s_setprio(1);
    QROW(0, a0) QROW(1, a1) QROW(2, a2) QROW(3, a3)
    __builtin_amdgcn_s_setprio(0);
    __builtin_amdgcn_s_barrier();
    // p5: stage Bh1(kt0+2)->buf0; MFMA m4-7 @ kt1,s0
    if (!last) stageB(0, 1, 2 * t + 2);
    __builtin_amdgcn_s_barrier();
    __builtin_amdgcn_s_setprio(1);
    QROW(4, a4) QROW(5, a5) QROW(6, a6) QROW(7, a7)
    __builtin_amdgcn_s_setprio(0);
    __builtin_amdgcn_s_barrier();
    // p6: read buf1 s1 (12); MFMA m0-3 @ kt1,s1
    RD12(1, 1)
    __builtin_amdgcn_s_barrier();
    __builtin_amdgcn_s_setprio(1);
    QROW(0, a0) QROW(1, a1) QROW(2, a2) QROW(3, a3)
    __builtin_amdgcn_s_setprio(0);
    __builtin_amdgcn_s_barrier();
    // p7: stage A-halves(kt1+2)->buf1; counted vmcnt; MFMA m4-7 @ kt1,s1
    if (!last) {
      stageA(1, 0, kt1 + 2); stageA(1, 1, kt1 + 2);
      asm volatile("s_waitcnt vmcnt(4)" ::: "memory");  // kt0+2's A (p3) + B (p4,p5) landed
    }
    __builtin_amdgcn_s_barrier();
    __builtin_amdgcn_s_setprio(1);
    QROW(4, a4) QROW(5, a5) QROW(6, a6) QROW(7, a7)
    __builtin_amdgcn_s_setprio(0);
    __builtin_amdgcn_s_barrier();
  }

  // epilogue: C-write
#pragma unroll
  for (int mf = 0; mf < 8; ++mf) {
    int row_base = m0 + wm * 128 + mf * 16 + lhi * 4;
#pragma unroll
    for (int nf = 0; nf < 4; ++nf) {
      int col = n0 + wn * 64 + nf * 16 + l15;
#pragma unroll
      for (int r = 0; r < 4; ++r)
        C[(size_t)(row_base + r) * N + col] = f2b(acc[mf][nf][r]);
    }
  }
}

// ---------------- GEMM v3 (2-phase prefetch; used for proj N=1024) ----------------
__global__ __launch_bounds__(256) void gemm_bt3(const short* __restrict__ A,
                                                const short* __restrict__ BT,
                                                short* __restrict__ C,
                                                int K, int N) {
  __shared__ short As[2][128 * 32];
  __shared__ short Bs[2][128 * 32];
  const int tid = threadIdx.x;
  const int lane = tid & 63;
  const int w = tid >> 6;
  const int wr = (w >> 1) * 64, wc = (w & 1) * 64;
  const int m0 = blockIdx.y * 128;
  const int n0 = blockIdx.x * 128;
  const int l15 = lane & 15, lhi = lane >> 4;

  f32x4 acc[4][4] = {};

  auto STAGE = [&](int b, int k0) {
#pragma unroll
    for (int p = 0; p < 2; ++p) {
      int g = w * 128 + p * 64 + lane;
      int row = g >> 2;
      int cs = (g & 3) * 8;
      gl_lds16(A + (size_t)(m0 + row) * K + k0 + cs, &As[b][g * 8]);
      gl_lds16(BT + (size_t)(n0 + row) * K + k0 + cs, &Bs[b][g * 8]);
    }
  };

  const int nt = K >> 5;
  STAGE(0, 0);
  __syncthreads();
  int cur = 0;
  for (int t = 0; t < nt; ++t) {
    if (t + 1 < nt) STAGE(cur ^ 1, (t + 1) << 5);
    s16x8 af[4], bf[4];
#pragma unroll
    for (int m = 0; m < 4; ++m)
      af[m] = *(const s16x8*)(&As[cur][(wr + m * 16 + l15) * 32 + lhi * 8]);
#pragma unroll
    for (int n = 0; n < 4; ++n)
      bf[n] = *(const s16x8*)(&Bs[cur][(wc + n * 16 + l15) * 32 + lhi * 8]);
#pragma unroll
    for (int m = 0; m < 4; ++m)
#pragma unroll
      for (int n = 0; n < 4; ++n)
        acc[m][n] = __builtin_amdgcn_mfma_f32_16x16x32_bf16(af[m], bf[n], acc[m][n], 0, 0, 0);
    __syncthreads();
    cur ^= 1;
  }
#pragma unroll
  for (int m = 0; m < 4; ++m) {
    int row_base = m0 + wr + m * 16 + lhi * 4;
#pragma unroll
    for (int n = 0; n < 4; ++n) {
      int col = n0 + wc + n * 16 + l15;
#pragma unroll
      for (int r = 0; r < 4; ++r)
        C[(size_t)(row_base + r) * N + col] = f2b(acc[m][n][r]);
    }
  }
}

// ---------------- RMSNorm on Q (with 1/8*log2e scale) and K slices of QKV, in place ----------------
__global__ __launch_bounds__(256) void rmsnorm_qk(short* __restrict__ QKV,
                                                  const float* __restrict__ g) {
  int row = blockIdx.x;
  int which = blockIdx.y;  // 0 = q, 1 = k
  size_t base = (size_t)row * 3072 + (size_t)which * 1024;
  int t = threadIdx.x;
  s16x4 in = *(const s16x4*)(QKV + base + t * 4);
  float v[4];
  float ss = 0.f;
#pragma unroll
  for (int j = 0; j < 4; ++j) {
    v[j] = b2f(in[j]);
    ss += v[j] * v[j];
  }
#pragma unroll
  for (int m = 32; m >= 1; m >>= 1) ss += __shfl_xor(ss, m);
  __shared__ float red[4];
  if ((t & 63) == 0) red[t >> 6] = ss;
  __syncthreads();
  float tot = red[0] + red[1] + red[2] + red[3];
  float inv = rsqrtf(tot * (1.0f / 1024.0f) + 1e-6f);
  if (which == 0) inv *= 0.125f * 1.44269504f;  // fold 1/sqrt(hd) AND log2(e) into Q
  s16x4 out;
#pragma unroll
  for (int j = 0; j < 4; ++j) out[j] = f2b(v[j] * inv * g[t * 4 + j]);
  *(s16x4*)(&QKV[base + t * 4]) = out;
}

// ======== swapped-operand attention core (see R11 notes) ========
__global__ __launch_bounds__(256) void attn_causal4(const short* __restrict__ QKV,
                                                    const short* __restrict__ Vt,
                                                    short* __restrict__ Y,
                                                    int L, int Lpad) {
  const int h = blockIdx.y, s = blockIdx.z;
  const int q0 = blockIdx.x * 64;
  const int tid = threadIdx.x;
  const int lane = tid & 63, w = tid >> 6;
  const int l15 = lane & 15, lhi = lane >> 4;
  const int row0 = s * L;

  __shared__ short Ks[2][64][72];
  __shared__ short Vs[2][64][72];

  int qld = q0 + w * 16 + l15;
  if (qld > L - 1) qld = L - 1;
  const size_t qrow = (size_t)(row0 + qld) * 3072 + h * 64;
  s16x8 qf0 = *(const s16x8*)(QKV + qrow + lhi * 8);
  s16x8 qf1 = *(const s16x8*)(QKV + qrow + 32 + lhi * 8);

  float lsum = 0.f;
  f32x4 o[4];
#pragma unroll
  for (int d = 0; d < 4; ++d) o[d] = f32x4{0.f, 0.f, 0.f, 0.f};

  const short* Vbase = Vt + (size_t)(s * 16 + h) * 64 * Lpad;
  const int sA = (lhi & 1) * 32 + l15;
  const int sB = sA + 16;
  const int bh = lhi >> 1;

  s16x8 kreg[2], vreg[2];
#pragma unroll
  for (int p = 0; p < 2; ++p) {
    int g = tid + p * 256;
    int kr = g >> 3, cs = (g & 7) * 8;
    int krow = kr;
    if (krow > L - 1) krow = L - 1;
    kreg[p] = *(const s16x8*)(QKV + (size_t)(row0 + krow) * 3072 + 1024 + h * 64 + cs);
    vreg[p] = *(const s16x8*)(Vbase + (size_t)kr * Lpad + cs);
  }

  int buf = 0;
  for (int kb = 0; kb <= q0; kb += 64, buf ^= 1) {
#pragma unroll
    for (int p = 0; p < 2; ++p) {
      int g = tid + p * 256;
      int kr = g >> 3, cs = (g & 7) * 8;
      *(s16x8*)(&Ks[buf][kr][cs]) = kreg[p];
      *(s16x8*)(&Vs[buf][kr][cs]) = vreg[p];
    }
    __syncthreads();
    if (kb + 64 <= q0) {
#pragma unroll
      for (int p = 0; p < 2; ++p) {
        int g = tid + p * 256;
        int kr = g >> 3, cs = (g & 7) * 8;
        int krow = kb + 64 + kr;
        if (krow > L - 1) krow = L - 1;
        kreg[p] = *(const s16x8*)(QKV + (size_t)(row0 + krow) * 3072 + 1024 + h * 64 + cs);
        vreg[p] = *(const s16x8*)(Vbase + (size_t)kr * Lpad + kb + 64 + cs);
      }
    }

    f32x4 st[4];
#pragma unroll
    for (int n = 0; n < 4; ++n) {
      s16x8 k0 = *(const s16x8*)(&Ks[buf][n * 16 + l15][lhi * 8]);
      s16x8 k1 = *(const s16x8*)(&Ks[buf][n * 16 + l15][32 + lhi * 8]);
      f32x4 sa = f32x4{-SM_SHIFT, -SM_SHIFT, -SM_SHIFT, -SM_SHIFT};
      sa = __builtin_amdgcn_mfma_f32_16x16x32_bf16(k0, qf0, sa, 0, 0, 0);
      sa = __builtin_amdgcn_mfma_f32_16x16x32_bf16(k1, qf1, sa, 0, 0, 0);
      st[n] = sa;
    }

    if (kb == q0) {
      int q = q0 + w * 16 + l15;
#pragma unroll
      for (int n = 0; n < 4; ++n) {
#pragma unroll
        for (int r = 0; r < 4; ++r) {
          int key = kb + n * 16 + lhi * 4 + r;
          if (key > q) st[n][r] = -1e30f;
        }
      }
    }

    int wd[4][2];
#pragma unroll
    for (int n = 0; n < 4; ++n) {
      float p0 = fexp2(st[n][0]), p1 = fexp2(st[n][1]);
      float p2 = fexp2(st[n][2]), p3 = fexp2(st[n][3]);
      lsum += (p0 + p1) + (p2 + p3);
      wd[n][0] = cvtpk(p0, p1);
      wd[n][1] = cvtpk(p2, p3);
    }

#pragma unroll
    for (int kk = 0; kk < 2; ++kk) {
      int a0 = __shfl(wd[2 * kk][0], sA), a1 = __shfl(wd[2 * kk][1], sA);
      int a2 = __shfl(wd[2 * kk][0], sB), a3 = __shfl(wd[2 * kk][1], sB);
      int c0 = __shfl(wd[2 * kk + 1][0], sA), c1 = __shfl(wd[2 * kk + 1][1], sA);
      int c2 = __shfl(wd[2 * kk + 1][0], sB), c3 = __shfl(wd[2 * kk + 1][1], sB);
      int pw[4];
      pw[0] = bh ? c0 : a0;
      pw[1] = bh ? c1 : a1;
      pw[2] = bh ? c2 : a2;
      pw[3] = bh ? c3 : a3;
      s16x8 pa = *(const s16x8*)pw;
#pragma unroll
      for (int d = 0; d < 4; ++d) {
        s16x8 vf = *(const s16x8*)(&Vs[buf][d * 16 + l15][kk * 32 + lhi * 8]);
        o[d] = __builtin_amdgcn_mfma_f32_16x16x32_bf16(pa, vf, o[d], 0, 0, 0);
      }
    }
  }

  lsum += __shfl_xor(lsum, 16);
  lsum += __shfl_xor(lsum, 32);
  float lsq[4];
#pragma unroll
  for (int r = 0; r < 4; ++r) lsq[r] = __shfl(lsum, lhi * 4 + r);
#pragma unroll
  for (int d = 0; d < 4; ++d) {
#pragma unroll
    for (int r = 0; r < 4; ++r) {
      int qr = q0 + w * 16 + lhi * 4 + r;
      if (qr < L)
        Y[(size_t)(row0 + qr) * 1024 + h * 64 + d * 16 + l15] = f2b(o[d][r] / lsq[r]);
    }
  }
}

// ---------------- split-K causal attention (global, L=2064) ----------------
__global__ __launch_bounds__(256) void attn_split2(const short* __restrict__ QKV,
                                                   const short* __restrict__ Vt,
                                                   float* __restrict__ o_acc,
                                                   float* __restrict__ ls_acc) {
  const int qb = blockIdx.x;
  const int chunk = blockIdx.y;
  const int sh = blockIdx.z;
  const int t0 = chunk * CT;
  if (t0 > qb) return;
  const int t1 = min(t0 + CT, qb + 1);
  const int h = sh & 15, s = sh >> 4;
  const int q0 = qb * 64;
  const int tid = threadIdx.x;
  const int lane = tid & 63, w = tid >> 6;
  const int l15 = lane & 15, lhi = lane >> 4;
  const int row0 = s * LG;
  const int Lpad = 2112;

  __shared__ short Ks[2][64][72];
  __shared__ short Vs[2][64][72];

  int qld = q0 + w * 16 + l15;
  if (qld > LG - 1) qld = LG - 1;
  const size_t qrow = (size_t)(row0 + qld) * 3072 + h * 64;
  s16x8 qf0 = *(const s16x8*)(QKV + qrow + lhi * 8);
  s16x8 qf1 = *(const s16x8*)(QKV + qrow + 32 + lhi * 8);

  float lsum = 0.f;
  f32x4 o[4];
#pragma unroll
  for (int d = 0; d < 4; ++d) o[d] = f32x4{0.f, 0.f, 0.f, 0.f};

  const short* Vbase = Vt + (size_t)sh * 64 * Lpad;
  const int sA = (lhi & 1) * 32 + l15;
  const int sB = sA + 16;
  const int bh = lhi >> 1;

  s16x8 kreg[2], vreg[2];
  const int kb0 = t0 * 64;
#pragma unroll
  for (int p = 0; p < 2; ++p) {
    int g = tid + p * 256;
    int kr = g >> 3, cs = (g & 7) * 8;
    int krow = kb0 + kr;
    if (krow > LG - 1) krow = LG - 1;
    kreg[p] = *(const s16x8*)(QKV + (size_t)(row0 + krow) * 3072 + 1024 + h * 64 + cs);
    vreg[p] = *(const s16x8*)(Vbase + (size_t)kr * Lpad + kb0 + cs);
  }

  int buf = 0;
  for (int t = t0; t < t1; ++t, buf ^= 1) {
    const int kb = t * 64;
#pragma unroll
    for (int p = 0; p < 2; ++p) {
      int g = tid + p * 256;
      int kr = g >> 3, cs = (g & 7) * 8;
      *(s16x8*)(&Ks[buf][kr][cs]) = kreg[p];
      *(s16x8*)(&Vs[buf][kr][cs]) = vreg[p];
    }
    __syncthreads();
    if (t + 1 < t1) {
#pragma unroll
      for (int p = 0; p < 2; ++p) {
        int g = tid + p * 256;
        int kr = g >> 3, cs = (g & 7) * 8;
        int krow = kb + 64 + kr;
        if (krow > LG - 1) krow = LG - 1;
        kreg[p] = *(const s16x8*)(QKV + (size_t)(row0 + krow) * 3072 + 1024 + h * 64 + cs);
        vreg[p] = *(const s16x8*)(Vbase + (size_t)kr * Lpad + kb + 64 + cs);
      }
    }

    f32x4 st[4];
#pragma unroll
    for (int n = 0; n < 4; ++n) {
      s16x8 k0 = *(const s16x8*)(&Ks[buf][n * 16 + l15][lhi * 8]);
      s16x8 k1 = *(const s16x8*)(&Ks[buf][n * 16 + l15][32 + lhi * 8]);
      f32x4 sa = f32x4{-SM_SHIFT, -SM_SHIFT, -SM_SHIFT, -SM_SHIFT};
      sa = __builtin_amdgcn_mfma_f32_16x16x32_bf16(k0, qf0, sa, 0, 0, 0);
      sa = __builtin_amdgcn_mfma_f32_16x16x32_bf16(k1, qf1, sa, 0, 0, 0);
      st[n] = sa;
    }

    if (t == qb) {
      int q = q0 + w * 16 + l15;
#pragma unroll
      for (int n = 0; n < 4; ++n) {
#pragma unroll
        for (int r = 0; r < 4; ++r) {
          int key = kb + n * 16 + lhi * 4 + r;
          if (key > q) st[n][r] = -1e30f;
        }
      }
    }

    int wd[4][2];
#pragma unroll
    for (int n = 0; n < 4; ++n) {
      float p0 = fexp2(st[n][0]), p1 = fexp2(st[n][1]);
      float p2 = fexp2(st[n][2]), p3 = fexp2(st[n][3]);
      lsum += (p0 + p1) + (p2 + p3);
      wd[n][0] = cvtpk(p0, p1);
      wd[n][1] = cvtpk(p2, p3);
    }

#pragma unroll
    for (int kk = 0; kk < 2; ++kk) {
      int a0 = __shfl(wd[2 * kk][0], sA), a1 = __shfl(wd[2 * kk][1], sA);
      int a2 = __shfl(wd[2 * kk][0], sB), a3 = __shfl(wd[2 * kk][1], sB);
      int c0 = __shfl(wd[2 * kk + 1][0], sA), c1 = __shfl(wd[2 * kk + 1][1], sA);
      int c2 = __shfl(wd[2 * kk + 1][0], sB), c3 = __shfl(wd[2 * kk + 1][1], sB);
      int pw[4];
      pw[0] = bh ? c0 : a0;
      pw[1] = bh ? c1 : a1;
      pw[2] = bh ? c2 : a2;
      pw[3] = bh ? c3 : a3;
      s16x8 pa = *(const s16x8*)pw;
#pragma unroll
      for (int d = 0; d < 4; ++d) {
        s16x8 vf = *(const s16x8*)(&Vs[buf][d * 16 + l15][kk * 32 + lhi * 8]);
        o[d] = __builtin_amdgcn_mfma_f32_16x16x32_bf16(pa, vf, o[d], 0, 0, 0);
      }
    }
  }

  lsum += __shfl_xor(lsum, 16);
  lsum += __shfl_xor(lsum, 32);
  int qmy = q0 + w * 16 + l15;
  if (lhi == 0 && qmy < LG) atomicAdd(&ls_acc[(size_t)sh * LG + qmy], lsum);
#pragma unroll
  for (int r = 0; r < 4; ++r) {
    int qr = q0 + w * 16 + lhi * 4 + r;
    if (qr < LG) {
#pragma unroll
      for (int d = 0; d < 4; ++d)
        atomicAdd(&o_acc[((size_t)sh * LG + qr) * 64 + d * 16 + l15], o[d][r]);
    }
  }
}

// merge: Y = o_acc / ls_acc
__global__ __launch_bounds__(256) void attn_merge(const float* __restrict__ o_acc,
                                                  const float* __restrict__ ls_acc,
                                                  short* __restrict__ Y) {
  int sh = blockIdx.z * 16 + blockIdx.y;
  int s = sh >> 4, h = sh & 15;
  int row = blockIdx.x * 4 + (threadIdx.x >> 6);
  int col = threadIdx.x & 63;
  if (row < LG) {
    float inv = 1.0f / ls_acc[(size_t)sh * LG + row];
    float v = o_acc[((size_t)sh * LG + row) * 64 + col];
    Y[(size_t)(s * LG + row) * 1024 + h * 64 + col] = f2b(v * inv);
  }
}

// ---------------- fused gather/scatter ----------------
__global__ __launch_bounds__(256) void build_xl(const float* __restrict__ x,
                                                const float* __restrict__ lm,
                                                short* __restrict__ Xin) {
  int row = blockIdx.x;  // 0..4351
  int s = row / 272, r = row % 272;
  const float* src = (r < 16) ? lm + ((size_t)s * 16 + r) * 1024
                              : x + ((size_t)s * 256 + (r - 16)) * 1024;
  int t = threadIdx.x;
  f32x4 v = *(const f32x4*)(src + t * 4);
  s16x4 o;
#pragma unroll
  for (int j = 0; j < 4; ++j) o[j] = f2b(v[j]);
  *(s16x4*)(&Xin[(size_t)row * 1024 + t * 4]) = o;
}

__global__ __launch_bounds__(256) void split_local_build_xg(const short* __restrict__ Pout,
                                                            const float* __restrict__ mem_src,
                                                            float* __restrict__ lm_out,
                                                            short* __restrict__ Xin) {
  int row = blockIdx.x;
  int t = threadIdx.x;
  if (row < 4352) {
    int sr = row < 4128 ? row : 4127;
    int b = sr / 2064, r = sr % 2064;
    s16x4 o;
    if (r < 16) {
      f32x4 v = *(const f32x4*)(mem_src + ((size_t)(b * 16 + r)) * 1024 + t * 4);
#pragma unroll
      for (int j = 0; j < 4; ++j) o[j] = f2b(v[j]);
    } else {
      int f = b * 2048 + (r - 16);
      int pr = (f >> 8) * 272 + 16 + (f & 255);
      o = *(const s16x4*)(Pout + (size_t)pr * 1024 + t * 4);
    }
    *(s16x4*)(&Xin[(size_t)row * 1024 + t * 4]) = o;
  } else {
    int m = row - 4352;
    int pr = (m >> 4) * 272 + (m & 15);
    s16x4 v = *(const s16x4*)(Pout + (size_t)pr * 1024 + t * 4);
    f32x4 o;
#pragma unroll
    for (int j = 0; j < 4; ++j) o[j] = b2f(v[j]);
    *(f32x4*)(&lm_out[(size_t)m * 1024 + t * 4]) = o;
  }
}

__global__ __launch_bounds__(256) void split_global_build_xl(const short* __restrict__ Pout,
                                                             const float* __restrict__ lm_src,
                                                             float* __restrict__ mem_out,
                                                             short* __restrict__ Xin) {
  int row = blockIdx.x;
  int t = threadIdx.x;
  if (row < 4352) {
    int s = row / 272, r = row % 272;
    s16x4 o;
    if (r < 16) {
      f32x4 v = *(const f32x4*)(lm_src + ((size_t)(s * 16 + r)) * 1024 + t * 4);
#pragma unroll
      for (int j = 0; j < 4; ++j) o[j] = f2b(v[j]);
    } else {
      int f = s * 256 + (r - 16);
      int pr = (f >> 11) * 2064 + 16 + (f & 2047);
      o = *(const s16x4*)(Pout + (size_t)pr * 1024 + t * 4);
    }
    *(s16x4*)(&Xin[(size_t)row * 1024 + t * 4]) = o;
  } else {
    int m = row - 4352;
    int pr = (m >> 4) * 2064 + (m & 15);
    s16x4 v = *(const s16x4*)(Pout + (size_t)pr * 1024 + t * 4);
    f32x4 o;
#pragma unroll
    for (int j = 0; j < 4; ++j) o[j] = b2f(v[j]);
    *(f32x4*)(&mem_out[(size_t)m * 1024 + t * 4]) = o;
  }
}

__global__ __launch_bounds__(256) void split_global_final(const short* __restrict__ Pout,
                                                          float* __restrict__ out) {
  int f = blockIdx.x;
  int t = threadIdx.x;
  int pr = (f >> 11) * 2064 + 16 + (f & 2047);
  s16x4 v = *(const s16x4*)(Pout + (size_t)pr * 1024 + t * 4);
  f32x4 o;
#pragma unroll
  for (int j = 0; j < 4; ++j) o[j] = b2f(v[j]);
  *(f32x4*)(&out[(size_t)f * 1024 + t * 4]) = o;
}

// ---------------- orchestration ----------------
extern "C" void kernel_launch(void* const* d_in, const int* in_sizes, int n_in,
                              void* d_out, int out_size, void* d_ws, size_t ws_size,
                              hipStream_t stream) {
  const float* x_in = (const float*)d_in[0];
  const float* mem_in = (const float*)d_in[1];
  const float* lm_in = (const float*)d_in[2];
  const float* Wqkv_loc = (const float*)d_in[3];
  const float* Wproj_loc = (const float*)d_in[4];
  const float* g_loc = (const float*)d_in[5];
  const float* Wqkv_glob = (const float*)d_in[6];
  const float* Wproj_glob = (const float*)d_in[7];
  const float* g_glob = (const float*)d_in[8];

  // enable 128KB dynamic LDS for the 8-phase GEMM (immediate API call, not captured)
  static bool attr_set = false;
  if (!attr_set) {
    hipFuncSetAttribute((const void*)gemm_8ph,
                        hipFuncAttributeMaxDynamicSharedMemorySize, 131072);
    attr_set = true;
  }

  char* ws = (char*)d_ws;
  size_t off = 0;
  auto alloc = [&](size_t bytes) {
    char* p = ws + off;
    off += (bytes + 255) & ~(size_t)255;
    return p;
  };
  short* Wt = (short*)alloc((size_t)3072 * 1024 * 2);
  float* lm_cur = (float*)alloc((size_t)256 * 1024 * 4);
  float* mem_cur = (float*)alloc((size_t)32 * 1024 * 4);
  short* Xin = (short*)alloc((size_t)MPAD * 1024 * 2);
  short* QKVb = (short*)alloc((size_t)MPAD * 3072 * 2);
  short* Yb = (short*)alloc((size_t)MPAD * 1024 * 2);
  short* Pout = (short*)alloc((size_t)MPAD * 1024 * 2);
  short* Vtb = (short*)alloc((size_t)256 * 64 * 320 * 2);
  size_t oacc_bytes = (size_t)32 * LG * 64 * 4;
  size_t lacc_bytes = (size_t)32 * LG * 4;
  float* o_acc = (float*)alloc(oacc_bytes);
  float* ls_acc = (float*)alloc(lacc_bytes);
  const bool use_split = (ws_size >= off);

  for (int i = 0; i < 2; ++i) {
    // ---- local attention (16 seqs, L=272, rows = 4352 = MPAD) ----
    transpose_cast<<<dim3(96, 32), dim3(32, 8), 0, stream>>>(
        Wqkv_loc + (size_t)i * 1024 * 3072, Wt, 1024, 3072);
    if (i == 0) build_xl<<<4352, 256, 0, stream>>>(x_in, lm_in, Xin);
    gemm_8ph<<<dim3(12, 17), 512, 131072, stream>>>(Xin, Wt, QKVb, 1024, 3072);
    rmsnorm_qk<<<dim3(4352, 2), 256, 0, stream>>>(QKVb, g_loc + (size_t)i * 1024);
    transpose_v<<<dim3(10, 2, 256), dim3(32, 8), 0, stream>>>(QKVb, Vtb, 272, 320);
    attn_causal4<<<dim3(5, 16, 16), 256, 0, stream>>>(QKVb, Vtb, Yb, 272, 320);
    transpose_cast<<<dim3(32, 32), dim3(32, 8), 0, stream>>>(
        Wproj_loc + (size_t)i * 1024 * 1024, Wt, 1024, 1024);
    gemm_bt3<<<dim3(8, 34), 256, 0, stream>>>(Yb, Wt, Pout, 1024, 1024);
    split_local_build_xg<<<4608, 256, 0, stream>>>(Pout, i == 0 ? mem_in : mem_cur,
                                                   lm_cur, Xin);

    // ---- global attention (2 seqs, L=2064, rows = 4128; pads deterministic) ----
    transpose_cast<<<dim3(96, 32), dim3(32, 8), 0, stream>>>(
        Wqkv_glob + (size_t)i * 1024 * 3072, Wt, 1024, 3072);
    gemm_8ph<<<dim3(12, 17), 512, 131072, stream>>>(Xin, Wt, QKVb, 1024, 3072);
    rmsnorm_qk<<<dim3(4128, 2), 256, 0, stream>>>(QKVb, g_glob + (size_t)i * 1024);
    transpose_v<<<dim3(66, 2, 32), dim3(32, 8), 0, stream>>>(QKVb, Vtb, 2064, 2112);
    if (use_split) {
      hipMemsetAsync(o_acc, 0, oacc_bytes, stream);
      hipMemsetAsync(ls_acc, 0, lacc_bytes, stream);
      attn_split2<<<dim3(33, 5, 32), 256, 0, stream>>>(QKVb, Vtb, o_acc, ls_acc);
      attn_merge<<<dim3(516, 16, 2), 256, 0, stream>>>(o_acc, ls_acc, Yb);
    } else {
      attn_causal4<<<dim3(33, 16, 2), 256, 0, stream>>>(QKVb, Vtb, Yb, 2064, 2112);
    }
    transpose_cast<<<dim3(32, 32), dim3(32, 8), 0, stream>>>(
        Wproj_glob + (size_t)i * 1024 * 1024, Wt, 1024, 1024);
    gemm_bt3<<<dim3(8, 34), 256, 0, stream>>>(Yb, Wt, Pout, 1024, 1024);
    if (i == 0)
      split_global_build_xl<<<4384, 256, 0, stream>>>(Pout, lm_cur, mem_cur, Xin);
    else
      split_global_final<<<4096, 256, 0, stream>>>(Pout, (float*)d_out);
  }
}